// Round 2
// baseline (7449.920 us; speedup 1.0000x reference)
//
#include <hip/hip_runtime.h>
#include <math.h>

// TNO block, fully frequency-domain pipeline, round 2:
// banded/panelled DFT kernels for occupancy (grid >= 1024), tiny LDS,
// scalar-uniform twiddle loads, separate cheap IN epilogue kernels.
//
// Spectra layout A[ky*65+kx] per map, forward-normalized:
//   x[y][n] = sum_full A e^{+2pi i (ky y + kx n)/128}
// irfft2 Im-drop semantics: y = Re( sum_ky sum_{kx<=64} w(kx) A e^{+i...} ),
// w = 1 at kx in {0,64}, else 2.

#define F128 8320   // 128*65

__device__ __forceinline__ void blockReduce2(float& a, float& b, float* red){
  int tid = threadIdx.x;
  red[tid] = a; red[256+tid] = b;
  __syncthreads();
  for(int off=128; off>0; off>>=1){
    if(tid<off){ red[tid]+=red[tid+off]; red[256+tid]+=red[256+tid+off]; }
    __syncthreads();
  }
  a = red[0]; b = red[256];
  __syncthreads();
}

// ---------------- twiddle table: CS[a*128+b] = (cos, sin)(2pi a b/128) ----------
__global__ void k_tables(float2* __restrict__ CS){
  int a = blockIdx.x, b = threadIdx.x;
  int p = (a*b)&127;
  float t = (float)p * (1.0f/64.0f);
  CS[a*128+b] = make_float2(cospif(t), sinpif(t));
}

// ---------------- per-map instance-norm stats of x -> sc1, dc1 ----------------
__global__ __launch_bounds__(256) void k_instats(
    const float* __restrict__ xin, const float* __restrict__ n1w,
    const float* __restrict__ n1b, float* __restrict__ sc, float* __restrict__ dc)
{
  __shared__ float red[512];
  const int m = blockIdx.x, t = threadIdx.x;
  const size_t mb = (size_t)m*16384;
  float s1=0.f, s2=0.f;
  for(int i=t;i<16384;i+=256){ float v = xin[mb+i]; s1+=v; s2+=v*v; }
  blockReduce2(s1,s2,red);
  if(t==0){
    float mu = s1*(1.0f/16384.0f);
    float var = s2*(1.0f/16384.0f)-mu*mu;
    sc[m] = n1w[0]*rsqrtf(var+1e-5f)*(1.0f/16384.0f);
    dc[m] = n1b[0];
  }
}

// ---------------- rfft2, banded: block = (map, 16-ky panel), 128 threads -------
// A = scale * DFT(x); scale = sc[m] (or 1/16384); DC forced to dc[m] when sc given.
__global__ __launch_bounds__(128) void k_rfft2b(
    const float* __restrict__ xin, float* __restrict__ Are, float* __restrict__ Aim,
    const float2* __restrict__ CS,
    const float* __restrict__ sc, const float* __restrict__ dc)
{
  __shared__ float2 Tt[16*128];     // [kyl][n]
  const int bid = blockIdx.x;
  const int m = bid>>3, pb = (bid&7)<<4;
  const int t = threadIdx.x;        // = n
  const float* xp = xin + (size_t)m*16384;

  // step1: T[ky][n] = sum_y x[y][n] e^{-2pi i ky y/128}; twiddles are uniform -> s_load
  float tr[16], ti[16];
  #pragma unroll
  for(int q=0;q<16;q++){ tr[q]=0.f; ti[q]=0.f; }
  for(int y=0;y<128;y++){
    float xv = xp[y*128 + t];
    #pragma unroll
    for(int q=0;q<16;q++){
      float2 cs = CS[(pb+q)*128 + y];
      tr[q] += cs.x*xv;
      ti[q] -= cs.y*xv;
    }
  }
  #pragma unroll
  for(int q=0;q<16;q++) Tt[q*128+t] = make_float2(tr[q], ti[q]);
  __syncthreads();

  const float scale = sc ? sc[m] : (1.0f/16384.0f);
  const size_t mb = (size_t)m*F128;

  // step2: A[ky][kx] = sum_n T[ky][n] e^{-2pi i kx n/128}
  const int kx = t&63, h = t>>6;    // thread: kx, kyl = h*8+q
  float ar[8], ai[8];
  #pragma unroll
  for(int q=0;q<8;q++){ ar[q]=0.f; ai[q]=0.f; }
  for(int n=0;n<128;n++){
    float2 cs = CS[n*128 + kx];     // lanes contiguous
    #pragma unroll
    for(int q=0;q<8;q++){
      float2 T = Tt[(h*8+q)*128 + n];   // wave-uniform broadcast
      ar[q] += T.x*cs.x + T.y*cs.y;
      ai[q] += T.y*cs.x - T.x*cs.y;
    }
  }
  #pragma unroll
  for(int q=0;q<8;q++){
    int ky = pb + h*8 + q;
    Are[mb + ky*65 + kx] = ar[q]*scale;
    Aim[mb + ky*65 + kx] = ai[q]*scale;
  }
  // kx = 64 column: e^{-i pi n} = (-1)^n -> alternating sum; threads t<16 (kyl=t)
  if(t<16){
    float sr=0.f, si=0.f;
    for(int n=0;n<128;n+=2){
      float2 a0 = Tt[t*128+n], a1 = Tt[t*128+n+1];
      sr += a0.x - a1.x;  si += a0.y - a1.y;
    }
    int ky = pb + t;
    Are[mb + ky*65 + 64] = sr*scale;
    Aim[mb + ky*65 + 64] = si*scale;
  }
  if(sc && pb==0 && t==0){ Are[mb] = dc[m]; Aim[mb] = 0.f; }
}

// ---------------- irfft2, banded: block = (map, 32-row band), 256 threads ------
// mode 0: write raw y ; mode 1: write gelu(y)
__global__ __launch_bounds__(256) void k_irfft2b(
    const float* __restrict__ Are, const float* __restrict__ Aim,
    const float2* __restrict__ CS, const int mode, float* __restrict__ outp)
{
  __shared__ float2 Vt[16*32];      // [kxl][mmL]
  const int bid = blockIdx.x;
  const int m = bid>>2, mb = (bid&3)<<5;
  const int t = threadIdx.x;
  const size_t amb = (size_t)m*F128;
  const int n = t&127, rg = t>>7;   // phase B: column n, rows rg*16..+15
  const int mmL = t&31, kg = t>>5;  // phase A: row mmL, kxl = kg*2+{0,1}
  float yacc[16];
  #pragma unroll
  for(int r=0;r<16;r++) yacc[r]=0.f;

  for(int pb=0; pb<65; pb+=16){
    const int psz = (pb==64)?1:16;
    // phase A: V[mm][kx] = sum_ky A[ky][kx] e^{+2pi i ky mm/128}
    float vr[2], vi[2];
    vr[0]=vr[1]=vi[0]=vi[1]=0.f;
    for(int ky=0; ky<128; ky++){
      float2 cs = CS[ky*128 + mb + mmL];
      #pragma unroll
      for(int kk=0;kk<2;kk++){
        int kxl = kg*2+kk;
        if(kxl<psz){
          float ar2 = Are[amb + ky*65 + pb + kxl];
          float ai2 = Aim[amb + ky*65 + pb + kxl];
          vr[kk] += ar2*cs.x - ai2*cs.y;
          vi[kk] += ar2*cs.y + ai2*cs.x;
        }
      }
    }
    __syncthreads();   // previous panel's phase B finished reading Vt
    #pragma unroll
    for(int kk=0;kk<2;kk++){
      int kxl = kg*2+kk;
      if(kxl<psz){
        int kx = pb+kxl;
        float w = (kx==0||kx==64)?1.0f:2.0f;
        Vt[kxl*32 + mmL] = make_float2(vr[kk]*w, vi[kk]*w);
      }
    }
    __syncthreads();
    // phase B: y[mm][n] += Re(V e^{+2pi i kx n/128})
    for(int kxl=0;kxl<psz;kxl++){
      int kx = pb+kxl;
      float2 cs = CS[kx*128 + n];
      #pragma unroll
      for(int r=0;r<16;r++){
        float2 v = Vt[kxl*32 + rg*16 + r];
        yacc[r] += v.x*cs.x - v.y*cs.y;
      }
    }
    __syncthreads();
  }
  const size_t ob = (size_t)m*16384;
  #pragma unroll
  for(int r=0;r<16;r++){
    float v = yacc[r];
    if(mode==1) v = 0.5f*v*(1.0f+erff(v*0.70710678118f));
    outp[ob + (size_t)(mb + rg*16 + r)*128 + n] = v;
  }
}

// ---------------- epilogue: attn = IN(y+x)*aw+ab ; emit h0-norm scales ---------
__global__ __launch_bounds__(256) void k_epi0(
    const float* __restrict__ yraw, const float* __restrict__ xsrc,
    const float* __restrict__ aw, const float* __restrict__ ab,
    const float* __restrict__ n2w, const float* __restrict__ n2b,
    float* __restrict__ attn, float* __restrict__ sc2, float* __restrict__ dc2)
{
  __shared__ float red[512];
  const int m = blockIdx.x, t = threadIdx.x;
  const size_t mb = (size_t)m*16384;
  float s1=0.f, s2=0.f;
  for(int i=t;i<16384;i+=256){ float v = yraw[mb+i]+xsrc[mb+i]; s1+=v; s2+=v*v; }
  blockReduce2(s1,s2,red);
  float mu = s1*(1.0f/16384.0f);
  float var = s2*(1.0f/16384.0f)-mu*mu;
  float rs = rsqrtf(var+1e-5f);
  float w = aw[0], b = ab[0];
  for(int i=t;i<16384;i+=256){
    float v = yraw[mb+i]+xsrc[mb+i];
    attn[mb+i] = (v-mu)*rs*w + b;
  }
  if(t==0){
    float va = w*w*var/(var+1e-5f);          // exact var of the attn map
    sc2[m] = n2w[m&3]*rsqrtf(va+1e-5f)*(1.0f/16384.0f);
    dc2[m] = n2b[m&3];
  }
}

// ---------------- epilogue: out = IN(y2)*mw+mb + attn --------------------------
__global__ __launch_bounds__(256) void k_epi2(
    const float* __restrict__ yraw, const float* __restrict__ attn,
    const float* __restrict__ mw, const float* __restrict__ mbv,
    float* __restrict__ outp)
{
  __shared__ float red[512];
  const int m = blockIdx.x, t = threadIdx.x;
  const size_t mb = (size_t)m*16384;
  float s1=0.f, s2=0.f;
  for(int i=t;i<16384;i+=256){ float v = yraw[mb+i]; s1+=v; s2+=v*v; }
  blockReduce2(s1,s2,red);
  float mu = s1*(1.0f/16384.0f);
  float var = s2*(1.0f/16384.0f)-mu*mu;
  float rs = rsqrtf(var+1e-5f);
  float w = mw[m&3], b = mbv[m&3];
  for(int i=t;i<16384;i+=256){
    outp[mb+i] = (yraw[mb+i]-mu)*rs*w + b + attn[mb+i];
  }
}

// ---------------- K/Q spectra on the 64-grid (trunc + corners + Pi proj) ----------
__global__ __launch_bounds__(256) void k_build_qk(
  const float* __restrict__ Xnre, const float* __restrict__ Xnim,
  const float* __restrict__ kqv_wr, const float* __restrict__ kqv_wi,
  const float* __restrict__ kqv_bias, const float* __restrict__ kqv_sw, const float* __restrict__ kqv_sb,
  float* __restrict__ Qre, float* __restrict__ Qim,
  float* __restrict__ Kre, float* __restrict__ Kim)
{
  __shared__ float Tre[2112], Tim[2112];
  __shared__ float Qr[2112], Qi[2112], Kr[2112], Ki[2112];
  const int bid = blockIdx.x;
  const int m = bid>>3, o = bid&7;
  const int tid = threadIdx.x;
  for(int j=tid;j<2112;j+=256){
    int r = j/33, c = j - r*33;
    int ky = (r<32)? r : r+64;
    Tre[j] = Xnre[(size_t)m*F128 + ky*65 + c];
    Tim[j] = Xnim[(size_t)m*F128 + ky*65 + c];
  }
  __syncthreads();
  const float swK = kqv_sw[o];
  const float swQ = kqv_sw[8+o];
  for(int j=tid;j<2112;j+=256){
    int r = j/33, c = j - r*33;
    float tr = Tre[j], ti = Tim[j];
    float kr = swK*tr, ki2 = swK*ti;
    float qr = swQ*tr, qi = swQ*ti;
    if(c<8){
      int wrow = (r<8)? r : ((r>=56)? 8+(r-56) : -1);
      if(wrow>=0){
        float wkr = kqv_wr[(o*16+wrow)*8+c],      wki = kqv_wi[(o*16+wrow)*8+c];
        kr += wkr*tr - wki*ti; ki2 += wkr*ti + wki*tr;
        float wqr = kqv_wr[((8+o)*16+wrow)*8+c],  wqi = kqv_wi[((8+o)*16+wrow)*8+c];
        qr += wqr*tr - wqi*ti; qi += wqr*ti + wqi*tr;
      }
    }
    if(j==0){
      kr += kqv_bias[o]   + kqv_sb[o];
      qr += kqv_bias[8+o] + kqv_sb[8+o];
    }
    Kr[j]=kr; Ki[j]=ki2; Qr[j]=qr; Qi[j]=qi;
  }
  __syncthreads();
  const size_t obase = ((size_t)(m*8+o))*2112;
  for(int j=tid;j<2112;j+=256){
    int r = j/33, c = j - r*33;
    float kr=Kr[j], ki2=Ki[j], qr=Qr[j], qi=Qi[j];
    float wsc = 128.0f;
    if(c==0 || c==32){
      int pj = ((64-r)&63)*33 + c;
      kr = 0.5f*(Kr[j]+Kr[pj]); ki2 = 0.5f*(Ki[j]-Ki[pj]);
      qr = 0.5f*(Qr[j]+Qr[pj]); qi  = 0.5f*(Qi[j]-Qi[pj]);
      wsc = 64.0f;
    }
    Qre[obase+j]=qr; Qim[obase+j]=qi;
    Kre[obase+j]=kr*wsc; Kim[obase+j]=ki2*wsc;
  }
}

// ---------------- scores via Parseval ----------
__global__ __launch_bounds__(256) void k_scores(
  const float* __restrict__ Qre, const float* __restrict__ Qim,
  const float* __restrict__ Kre, const float* __restrict__ Kim,
  float* __restrict__ P)
{
  __shared__ float Klr[128*65], Kli[128*65];
  __shared__ float Qlr[8*65],  Qli[8*65];
  const int bid = blockIdx.x;
  const int b = bid>>7, h = (bid>>4)&7, tt = bid&15;
  const int tid = threadIdx.x;
  const int ts = tid>>5, ss = tid&31;
  float acc[4] = {0.f,0.f,0.f,0.f};
  for(int ch=0; ch<33; ch++){
    const int fb = ch*64;
    __syncthreads();
    for(int idx=tid; idx<128*64; idx+=256){
      int s = idx>>6, fl = idx&63;
      size_t off = ((size_t)((b*128+s)*8+h))*2112 + fb + fl;
      Klr[s*65+fl] = Kre[off]; Kli[s*65+fl] = Kim[off];
    }
    for(int idx=tid; idx<8*64; idx+=256){
      int t = idx>>6, fl = idx&63;
      size_t off = ((size_t)((b*128+tt*8+t)*8+h))*2112 + fb + fl;
      Qlr[t*65+fl] = Qre[off]; Qli[t*65+fl] = Qim[off];
    }
    __syncthreads();
    for(int f=0; f<64; f++){
      float qr = Qlr[ts*65+f], qi = Qli[ts*65+f];
      #pragma unroll
      for(int k=0;k<4;k++){
        int s = k*32+ss;
        acc[k] += qr*Klr[s*65+f] + qi*Kli[s*65+f];
      }
    }
  }
  const int t = tt*8+ts;
  #pragma unroll
  for(int k=0;k<4;k++){
    int s = k*32+ss;
    P[((size_t)((b*8+h)*128+t))*128 + s] = acc[k];
  }
}

__global__ __launch_bounds__(64) void k_softmax(float* __restrict__ P){
  const int row = blockIdx.x, tid = threadIdx.x;
  float* p = P + (size_t)row*128;
  float v0 = p[tid], v1 = p[tid+64];
  float mx = fmaxf(v0,v1);
  for(int off=32; off; off>>=1) mx = fmaxf(mx, __shfl_xor(mx, off));
  float e0 = expf(v0-mx), e1 = expf(v1-mx);
  float s = e0+e1;
  for(int off=32; off; off>>=1) s += __shfl_xor(s, off);
  float inv = 1.0f/s;
  p[tid] = e0*inv; p[tid+64] = e1*inv;
}

__global__ __launch_bounds__(256) void k_peff(const float* __restrict__ P,
   const float* __restrict__ p_sw, const float* __restrict__ kqv_sw,
   float* __restrict__ Peff)
{
  const int i = blockIdx.x*256 + threadIdx.x;
  const int b = i>>14, rem = i&16383;
  float acc=0.f;
  for(int hh=0; hh<8; hh++){
    float a = p_sw[hh]*kqv_sw[16+hh];
    acc += a * P[(((size_t)(b*8+hh))<<14) + rem];
  }
  Peff[i] = acc;
}

__global__ __launch_bounds__(256) void k_gather(
   const float* __restrict__ Xnre, const float* __restrict__ Xnim,
   float* __restrict__ Xpr, float* __restrict__ Xpi)
{
  const int m = blockIdx.x, tid = threadIdx.x;
  for(int j=tid;j<512;j+=256){
    int r = j>>4, c = j&15;
    int ky = (r<16)? r : 96+r;
    size_t f = (size_t)m*F128 + ky*65 + c;
    Xpr[m*512+j] = Xnre[f]; Xpi[m*512+j] = Xnim[f];
  }
}

__global__ __launch_bounds__(256) void k_zp(const float* __restrict__ P,
  const float* __restrict__ Xpr, const float* __restrict__ Xpi,
  float* __restrict__ Zr, float* __restrict__ Zi)
{
  __shared__ float Pt[2048];
  const int bid = blockIdx.x;
  const int b = bid>>6, o = (bid>>3)&7, ct = bid&7;
  const int tid = threadIdx.x;
  for(int idx=tid; idx<2048; idx+=256){
    int cl = idx>>7, s = idx&127;
    Pt[cl*128+s] = P[((size_t)((b*8+o)*128 + ct*16+cl))*128 + s];
  }
  __syncthreads();
  for(int it=0; it<2; it++){
    int j = tid + it*256;
    float ar[16], ai[16];
    #pragma unroll
    for(int c=0;c<16;c++){ ar[c]=0.f; ai[c]=0.f; }
    for(int s=0;s<128;s++){
      float xr = Xpr[(b*128+s)*512 + j];
      float xi = Xpi[(b*128+s)*512 + j];
      #pragma unroll
      for(int c=0;c<16;c++){
        float pv = Pt[c*128+s];
        ar[c] += pv*xr; ai[c] += pv*xi;
      }
    }
    #pragma unroll
    for(int c=0;c<16;c++){
      size_t off = ((size_t)((b*8+o)*128 + ct*16+c))*512 + j;
      Zr[off]=ar[c]; Zi[off]=ai[c];
    }
  }
}

__global__ __launch_bounds__(256) void k_big(const float* __restrict__ Peff,
  const float* __restrict__ Xnre, const float* __restrict__ Xnim,
  float* __restrict__ Br, float* __restrict__ Bi)
{
  __shared__ float Pt[2048];
  const int bid = blockIdx.x;
  const int b = bid>>6, ct = (bid>>3)&7, fc = bid&7;
  const int tid = threadIdx.x;
  for(int idx=tid; idx<2048; idx+=256){
    int cl = idx>>7, s = idx&127;
    Pt[cl*128+s] = Peff[((size_t)(b*128 + ct*16+cl))*128 + s];
  }
  __syncthreads();
  const int fb = fc*1040;
  for(int it=0; it<5; it++){
    int j = fb + tid + it*256;
    if(j >= fb+1040) break;
    float ar[16], ai[16];
    #pragma unroll
    for(int c=0;c<16;c++){ ar[c]=0.f; ai[c]=0.f; }
    for(int s=0;s<128;s++){
      float xr = Xnre[(size_t)(b*128+s)*F128 + j];
      float xi = Xnim[(size_t)(b*128+s)*F128 + j];
      #pragma unroll
      for(int c=0;c<16;c++){
        float pv = Pt[c*128+s];
        ar[c] += pv*xr; ai[c] += pv*xi;
      }
    }
    #pragma unroll
    for(int c=0;c<16;c++){
      size_t off = (size_t)(b*128+ct*16+c)*F128 + j;
      Br[off]=ar[c]; Bi[off]=ai[c];
    }
  }
}

__global__ __launch_bounds__(256) void k_corr(
  const float* __restrict__ Zr, const float* __restrict__ Zi,
  const float* __restrict__ kqv_wr, const float* __restrict__ kqv_wi,
  const float* __restrict__ kqv_bias, const float* __restrict__ kqv_sw, const float* __restrict__ kqv_sb,
  const float* __restrict__ p_wr, const float* __restrict__ p_wi,
  const float* __restrict__ p_bias, const float* __restrict__ p_sw, const float* __restrict__ p_sb,
  float* __restrict__ Br, float* __restrict__ Bi)
{
  const int m = blockIdx.x;
  const int b = m>>7, cix = m&127;
  const int tid = threadIdx.x;
  for(int j=tid; j<512; j+=256){
    int r = j>>4, c = j&15;
    int ky = (r<16)? r : 96+r;
    float accr=0.f, acci=0.f;
    int rp = -1;
    if(c==0){ int kyp = (128-ky)&127; rp = (kyp<16)? kyp : ((kyp>=112)? kyp-96 : -1); }
    for(int o=0;o<8;o++){
      size_t zoff = ((size_t)((b*8+o)*128 + cix))*512;
      float zr = Zr[zoff+j], zi = Zi[zoff+j];
      float cvr=0.f, cvi=0.f;
      bool inV = (c<8) && (ky<8 || ky>=120);
      if(inV){
        int vrow = (ky<8)? ky : 8+(ky-120);
        float wr = kqv_wr[((16+o)*16+vrow)*8+c], wi = kqv_wi[((16+o)*16+vrow)*8+c];
        cvr = wr*zr - wi*zi; cvi = wr*zi + wi*zr;
      }
      float ar = cvr, ai = cvi;
      if(c==0){
        float pvr=0.f, pvi=0.f;
        int kyp = (128-ky)&127;
        bool pInV = (kyp<8 || kyp>=120);
        if(pInV && rp>=0){
          int vrow = (kyp<8)? kyp : 8+(kyp-120);
          float zr2 = Zr[zoff + rp*16], zi2 = Zi[zoff + rp*16];
          float wr = kqv_wr[((16+o)*16+vrow)*8], wi = kqv_wi[((16+o)*16+vrow)*8];
          pvr = wr*zr2 - wi*zi2; pvi = wr*zi2 + wi*zr2;
        }
        ar = 0.5f*(cvr + pvr);
        ai = 0.5f*(cvi - pvi);
      }
      float sv = kqv_sw[16+o];
      float Dv = kqv_bias[16+o] + kqv_sb[16+o];
      float atr = sv*zr + ar + ((j==0)? Dv : 0.f);
      float ati = sv*zi + ai;
      float psw = p_sw[o];
      accr += psw*ar;  acci += psw*ai;
      float wpr = p_wr[(o*32+r)*16+c], wpi = p_wi[(o*32+r)*16+c];
      accr += wpr*atr - wpi*ati;
      acci += wpr*ati + wpi*atr;
      if(j==0) accr += psw*Dv;
    }
    if(j==0) accr += p_bias[0] + p_sb[0];
    size_t f = (size_t)m*F128 + ky*65 + c;
    Br[f] += accr; Bi[f] += acci;
  }
}

__global__ __launch_bounds__(256) void k_mix(
  const float* __restrict__ Hre, const float* __restrict__ Him,
  const float* __restrict__ wr0, const float* __restrict__ wi0,
  const float* __restrict__ msw, const float* __restrict__ msb,
  float* __restrict__ Ore, float* __restrict__ Oim)
{
  __shared__ float scr[512], sci[512];
  __shared__ float red[512];
  const int bid = blockIdx.x;
  const int g = bid>>2, o = bid&3;
  const int tid = threadIdx.x;
  for(int j=tid;j<512;j+=256){
    int r=j>>4, c=j&15;
    int ky = (r<16)? r : 96+r;
    int f = ky*65+c;
    float ar=0.f, ai=0.f;
    for(int i2=0;i2<4;i2++){
      float hr = Hre[(size_t)(g*4+i2)*F128+f], hi = Him[(size_t)(g*4+i2)*F128+f];
      float wr = wr0[((i2*4+o)*32+r)*16+c],   wi = wi0[((i2*4+o)*32+r)*16+c];
      ar += wr*hr - wi*hi; ai += wr*hi + wi*hr;
    }
    scr[j]=ar; sci[j]=ai;
  }
  __syncthreads();
  float vs=0.f, dummy=0.f;
  for(int j=tid;j<512;j+=256){
    int c=j&15;
    if(c>=1) vs += 2.0f*(scr[j]*scr[j]+sci[j]*sci[j]);
  }
  if(tid<32){
    int ky = (tid<16)? (tid+1) : (96+tid);
    float ar=0.f, ai=0.f;
    if(ky<16){ ar=scr[ky*16]; ai=sci[ky*16]; }
    else if(ky>=112){ int r=ky-96; ar=scr[r*16]; ai=sci[r*16]; }
    int kyp = 128-ky;
    float br2=0.f, bi2=0.f;
    if(kyp<16){ br2=scr[kyp*16]; bi2=sci[kyp*16]; }
    else if(kyp>=112){ int r=kyp-96; br2=scr[r*16]; bi2=sci[r*16]; }
    float pr = 0.5f*(ar+br2), pi = 0.5f*(ai-bi2);
    vs += pr*pr + pi*pi;
  }
  blockReduce2(vs, dummy, red);
  float rs2 = rsqrtf(vs + 1e-5f);
  for(int f=tid; f<F128; f+=256){
    int ky = f/65, c = f - ky*65;
    float skr=0.f, ski=0.f;
    for(int i2=0;i2<4;i2++){
      float sw = msw[o*4+i2];
      skr += sw*Hre[(size_t)(g*4+i2)*F128+f];
      ski += sw*Him[(size_t)(g*4+i2)*F128+f];
    }
    if(f==0) skr += msb[o];
    if(c<16){
      int r = (ky<16)? ky : ((ky>=112)? ky-96 : -1);
      if(r>=0){
        int j = r*16+c;
        if(j!=0){ skr += rs2*scr[j]; ski += rs2*sci[j]; }
      }
    }
    Ore[(size_t)(g*4+o)*F128+f] = skr;
    Oim[(size_t)(g*4+o)*F128+f] = ski;
  }
}

extern "C" void kernel_launch(void* const* d_in, const int* in_sizes, int n_in,
                              void* d_out, int out_size, void* d_ws, size_t ws_size,
                              hipStream_t stream)
{
  const float* x        = (const float*)d_in[0];
  const float* norm1_w  = (const float*)d_in[1];
  const float* norm1_b  = (const float*)d_in[2];
  const float* kqv_wr   = (const float*)d_in[3];
  const float* kqv_wi   = (const float*)d_in[4];
  const float* kqv_bias = (const float*)d_in[5];
  const float* kqv_sw   = (const float*)d_in[6];
  const float* kqv_sb   = (const float*)d_in[7];
  const float* p_wr     = (const float*)d_in[8];
  const float* p_wi     = (const float*)d_in[9];
  const float* p_bias   = (const float*)d_in[10];
  const float* p_sw     = (const float*)d_in[11];
  const float* p_sb     = (const float*)d_in[12];
  const float* attn_norm_w = (const float*)d_in[13];
  const float* attn_norm_b = (const float*)d_in[14];
  const float* norm2_w  = (const float*)d_in[15];
  const float* norm2_b  = (const float*)d_in[16];
  const float* mix_wr   = (const float*)d_in[17];
  const float* mix_wi   = (const float*)d_in[18];
  // mix_bias (d_in[19]) only shifts the spectral mean which IN removes -> unused
  const float* mix_sw   = (const float*)d_in[20];
  const float* mix_sb   = (const float*)d_in[21];
  const float* mon_w    = (const float*)d_in[22];
  const float* mon_b    = (const float*)d_in[23];
  float* out = (float*)d_out;

  const size_t NEED = (size_t)28443648 * sizeof(float);
  if(ws_size < NEED) return;

  float* ws = (float*)d_ws;
  size_t off = 0;
  float2* CS  = (float2*)(ws + off); off += 32768;
  float* Xnre = ws + off; off += (size_t)256*F128;
  float* Xnim = ws + off; off += (size_t)256*F128;
  float* pool = ws + off; off += 17301504;
  float* P    = ws + off; off += 262144;
  float* Peff = ws + off; off += 32768;
  float* Xpr  = ws + off; off += 131072;
  float* Xpi  = ws + off; off += 131072;
  float* Zr   = ws + off; off += 1048576;
  float* Zi   = ws + off; off += 1048576;
  float* attn = ws + off; off += 4194304;
  float* sc1  = ws + off; off += 256;
  float* dc1  = ws + off; off += 256;
  float* sc2  = ws + off; off += 256;
  float* dc2  = ws + off; off += 256;

  float* Qre = pool;
  float* Qim = pool + 4325376;
  float* Kre = pool + 8650752;
  float* Kim = pool + 12976128;
  float* Br  = pool;                    // after scores (Q dead)
  float* Bi  = pool + 2129920;
  float* y0  = pool + 4325376;          // raw attn irfft (dead after epi0)
  float* h1fre = pool + 4325376;        // after y0 dead
  float* h1fim = pool + 6455296;
  float* h1g   = pool + 8650752;
  float* h1gfre= pool;                  // B dead after attn irfft
  float* h1gfim= pool + 2129920;
  float* h2fre = pool + 12976128;
  float* h2fim = pool + 15106048;
  float* y2  = pool;                    // h1gf dead after mix2
  float* h0fre = Xnre;                  // Xn dead once B/Zp consumed
  float* h0fim = Xnim;

  k_tables<<<dim3(128), dim3(128), 0, stream>>>(CS);
  k_instats<<<dim3(256), dim3(256), 0, stream>>>(x, norm1_w, norm1_b, sc1, dc1);
  // tok_n spectra (instance-norm folded)
  k_rfft2b<<<dim3(2048), dim3(128), 0, stream>>>(x, Xnre, Xnim, CS, sc1, dc1);
  // K,Q on 64-grid
  k_build_qk<<<dim3(2048), dim3(256), 0, stream>>>(Xnre, Xnim, kqv_wr, kqv_wi, kqv_bias, kqv_sw, kqv_sb,
                                                   Qre, Qim, Kre, Kim);
  k_scores<<<dim3(256), dim3(256), 0, stream>>>(Qre, Qim, Kre, Kim, P);
  k_softmax<<<dim3(2048), dim3(64), 0, stream>>>(P);
  k_peff<<<dim3(128), dim3(256), 0, stream>>>(P, p_sw, kqv_sw, Peff);
  k_gather<<<dim3(256), dim3(256), 0, stream>>>(Xnre, Xnim, Xpr, Xpi);
  k_zp<<<dim3(128), dim3(256), 0, stream>>>(P, Xpr, Xpi, Zr, Zi);
  k_big<<<dim3(128), dim3(256), 0, stream>>>(Peff, Xnre, Xnim, Br, Bi);
  k_corr<<<dim3(256), dim3(256), 0, stream>>>(Zr, Zi, kqv_wr, kqv_wi, kqv_bias, kqv_sw, kqv_sb,
                                              p_wr, p_wi, p_bias, p_sw, p_sb, Br, Bi);
  // attn = IN(irfft2(B) + tokens)
  k_irfft2b<<<dim3(1024), dim3(256), 0, stream>>>(Br, Bi, CS, 0, y0);
  k_epi0<<<dim3(256), dim3(256), 0, stream>>>(y0, x, attn_norm_w, attn_norm_b, norm2_w, norm2_b,
                                              attn, sc2, dc2);
  // h0 spectra (norm2 folded, scales precomputed analytically)
  k_rfft2b<<<dim3(2048), dim3(128), 0, stream>>>(attn, h0fre, h0fim, CS, sc2, dc2);
  // mixer layer 1 -> h1f ; gelu in spatial ; back to freq
  k_mix<<<dim3(256), dim3(256), 0, stream>>>(h0fre, h0fim, mix_wr, mix_wi, mix_sw, mix_sb, h1fre, h1fim);
  k_irfft2b<<<dim3(1024), dim3(256), 0, stream>>>(h1fre, h1fim, CS, 1, h1g);
  k_rfft2b<<<dim3(2048), dim3(128), 0, stream>>>(h1g, h1gfre, h1gfim, CS,
                                                 (const float*)nullptr, (const float*)nullptr);
  // mixer layer 2 -> h2f ; final: out = IN(irfft2(h2f))*mon + attn
  k_mix<<<dim3(256), dim3(256), 0, stream>>>(h1gfre, h1gfim, mix_wr+8192, mix_wi+8192, mix_sw+16, mix_sb+4,
                                             h2fre, h2fim);
  k_irfft2b<<<dim3(1024), dim3(256), 0, stream>>>(h2fre, h2fim, CS, 0, y2);
  k_epi2<<<dim3(256), dim3(256), 0, stream>>>(y2, attn, mon_w, mon_b, out);
}

// Round 3
// 596.103 us; speedup vs baseline: 12.4977x; 12.4977x over previous
//
#include <hip/hip_runtime.h>
#include <math.h>

// TNO block, round 3: no full-grid DFTs.
//  - xn (normalized tokens) only ever needed on the 64x33 truncation grid -> k_p1/k_p2
//  - attn spatial = Peff @ xn (GEMM) + corner-inverse of 512-mode correction spectrum
//  - mixer layers: skip = spatial affine combos; spectral = corner(32x16) DFT round trips
// Conventions: forward-normalized spectra, x[y][n] = sum A e^{+2pi i(ky y+kx n)/128}.

#define NT 2112   // 64*33 truncated spectrum per map

__device__ __forceinline__ void blockReduce2(float& a, float& b, float* red){
  int tid = threadIdx.x;
  red[tid] = a; red[256+tid] = b;
  __syncthreads();
  for(int off=128; off>0; off>>=1){
    if(tid<off){ red[tid]+=red[tid+off]; red[256+tid]+=red[256+tid+off]; }
    __syncthreads();
  }
  a = red[0]; b = red[256];
  __syncthreads();
}

// ---------------- twiddle table: CS[a*128+b] = (cos,sin)(2pi a b/128) ----------
__global__ void k_tables(float2* __restrict__ CS){
  int a = blockIdx.x, b = threadIdx.x;
  int p = (a*b)&127;
  float t = (float)p * (1.0f/64.0f);
  CS[a*128+b] = make_float2(cospif(t), sinpif(t));
}

// ---------------- per-map IN stats of x: alpha1 = w*rs, beta1 = b - mu*alpha ---
__global__ __launch_bounds__(256) void k_instats(
    const float* __restrict__ xin, const float* __restrict__ n1w,
    const float* __restrict__ n1b, float* __restrict__ a1, float* __restrict__ b1)
{
  __shared__ float red[512];
  const int m = blockIdx.x, t = threadIdx.x;
  const float* xp = xin + (size_t)m*16384;
  float s1=0.f, s2=0.f;
  for(int i=t;i<4096;i+=256){
    float4 v = ((const float4*)xp)[i];
    s1 += v.x+v.y+v.z+v.w;
    s2 += v.x*v.x+v.y*v.y+v.z*v.z+v.w*v.w;
  }
  blockReduce2(s1,s2,red);
  if(t==0){
    float mu = s1*(1.0f/16384.0f);
    float var = s2*(1.0f/16384.0f)-mu*mu;
    float a = n1w[0]*rsqrtf(var+1e-5f);
    a1[m] = a; b1[m] = n1b[0] - mu*a;
  }
}

// ---------------- k_p1: x-dim partial DFT (33 cols): R[y][c] -------------------
__global__ __launch_bounds__(256) void k_p1(
    const float* __restrict__ xin, float* __restrict__ R1r, float* __restrict__ R1i,
    const float2* __restrict__ CS)
{
  __shared__ float xl[32*129];
  __shared__ float2 csl[4224];
  const int bid = blockIdx.x;
  const int m = bid>>2, yt = bid&3;
  const int t = threadIdx.x;
  for(int i=t;i<4224;i+=256) csl[i] = CS[i];
  {
    const float4* xp4 = (const float4*)(xin + (size_t)m*16384 + yt*4096);
    for(int i4=t;i4<1024;i4+=256){
      float4 v = xp4[i4];
      int y = i4>>5, n = (i4&31)*4;
      xl[y*129+n]=v.x; xl[y*129+n+1]=v.y; xl[y*129+n+2]=v.z; xl[y*129+n+3]=v.w;
    }
  }
  __syncthreads();
  const int yl = t&31, cg = t>>5;
  const int nc = (cg==0)?5:4;
  float ar[5]={0,0,0,0,0}, ai[5]={0,0,0,0,0};
  for(int n=0;n<128;n++){
    float xv = xl[yl*129+n];
    #pragma unroll
    for(int k=0;k<5;k++){
      if(k<nc){
        float2 cs = csl[(cg+8*k)*128+n];
        ar[k] += xv*cs.x;
        ai[k] -= xv*cs.y;
      }
    }
  }
  __syncthreads();
  #pragma unroll
  for(int k=0;k<5;k++){
    if(k<nc){
      int c = cg+8*k;
      xl[yl*33+c] = ar[k];
      xl[1056 + yl*33+c] = ai[k];
    }
  }
  __syncthreads();
  const int gb = m*4224 + yt*1056;
  for(int idx=t; idx<2112; idx+=256){
    if(idx<1056) R1r[gb+idx] = xl[idx];
    else         R1i[gb+idx-1056] = xl[idx];
  }
}

// ---------------- k_p2: y-dim DFT -> Xt[r*33+c], r<32: ky=r else ky=r+64 -------
__global__ __launch_bounds__(320) void k_p2(
    const float* __restrict__ R1r, const float* __restrict__ R1i,
    const float2* __restrict__ CS, const float* __restrict__ a1,
    const float* __restrict__ n1b,
    float* __restrict__ Xtr, float* __restrict__ Xti)
{
  __shared__ float2 Rl[128*34];
  const int m = blockIdx.x, t = threadIdx.x;
  for(int idx=t; idx<4224; idx+=320){
    int y = idx/33, c = idx - y*33;
    Rl[y*34+c] = make_float2(R1r[m*4224+idx], R1i[m*4224+idx]);
  }
  __syncthreads();
  float ar[8], ai[8];
  int cc=0, rg=0;
  if(t<264){
    rg = t/33; cc = t - rg*33;
    int kys[8];
    #pragma unroll
    for(int k=0;k<8;k++){
      int r = rg + 8*k;
      kys[k] = (r<32)? r : r+64;
      ar[k]=0.f; ai[k]=0.f;
    }
    for(int y=0;y<128;y++){
      float2 Rv = Rl[y*34+cc];
      #pragma unroll
      for(int k=0;k<8;k++){
        int p = (kys[k]*y)&127;
        float2 cs = CS[128+p];
        ar[k] += Rv.x*cs.x + Rv.y*cs.y;
        ai[k] += Rv.y*cs.x - Rv.x*cs.y;
      }
    }
  }
  __syncthreads();
  if(t<264){
    #pragma unroll
    for(int k=0;k<8;k++){
      int r = rg + 8*k;
      Rl[r*33+cc] = make_float2(ar[k], ai[k]);
    }
  }
  __syncthreads();
  const float sc = a1[m]*(1.0f/16384.0f);
  for(int idx=t; idx<2112; idx+=320){
    float2 v = Rl[idx];
    float vr = v.x*sc, vi = v.y*sc;
    if(idx==0){ vr = n1b[0]; vi = 0.f; }
    Xtr[m*NT+idx] = vr; Xti[m*NT+idx] = vi;
  }
}

// ---------------- K/Q spectra on the 64-grid (trunc + corners + Pi proj) -------
__global__ __launch_bounds__(256) void k_build_qk(
  const float* __restrict__ Xtr, const float* __restrict__ Xti,
  const float* __restrict__ kqv_wr, const float* __restrict__ kqv_wi,
  const float* __restrict__ kqv_bias, const float* __restrict__ kqv_sw, const float* __restrict__ kqv_sb,
  float* __restrict__ Qre, float* __restrict__ Qim,
  float* __restrict__ Kre, float* __restrict__ Kim)
{
  __shared__ float Tre[2112], Tim[2112];
  __shared__ float Qr[2112], Qi[2112], Kr[2112], Ki[2112];
  const int bid = blockIdx.x;
  const int m = bid>>3, o = bid&7;
  const int tid = threadIdx.x;
  for(int j=tid;j<2112;j+=256){
    Tre[j] = Xtr[m*NT+j];
    Tim[j] = Xti[m*NT+j];
  }
  __syncthreads();
  const float swK = kqv_sw[o];
  const float swQ = kqv_sw[8+o];
  for(int j=tid;j<2112;j+=256){
    int r = j/33, c = j - r*33;
    float tr = Tre[j], ti = Tim[j];
    float kr = swK*tr, ki2 = swK*ti;
    float qr = swQ*tr, qi = swQ*ti;
    if(c<8){
      int wrow = (r<8)? r : ((r>=56)? 8+(r-56) : -1);
      if(wrow>=0){
        float wkr = kqv_wr[(o*16+wrow)*8+c],      wki = kqv_wi[(o*16+wrow)*8+c];
        kr += wkr*tr - wki*ti; ki2 += wkr*ti + wki*tr;
        float wqr = kqv_wr[((8+o)*16+wrow)*8+c],  wqi = kqv_wi[((8+o)*16+wrow)*8+c];
        qr += wqr*tr - wqi*ti; qi += wqr*ti + wqi*tr;
      }
    }
    if(j==0){
      kr += kqv_bias[o]   + kqv_sb[o];
      qr += kqv_bias[8+o] + kqv_sb[8+o];
    }
    Kr[j]=kr; Ki[j]=ki2; Qr[j]=qr; Qi[j]=qi;
  }
  __syncthreads();
  const size_t obase = ((size_t)(m*8+o))*NT;
  for(int j=tid;j<2112;j+=256){
    int r = j/33, c = j - r*33;
    float kr=Kr[j], ki2=Ki[j], qr=Qr[j], qi=Qi[j];
    float wsc = 128.0f;
    if(c==0 || c==32){
      int pj = ((64-r)&63)*33 + c;
      kr = 0.5f*(Kr[j]+Kr[pj]); ki2 = 0.5f*(Ki[j]-Ki[pj]);
      qr = 0.5f*(Qr[j]+Qr[pj]); qi  = 0.5f*(Qi[j]-Qi[pj]);
      wsc = 64.0f;
    }
    Qre[obase+j]=qr; Qim[obase+j]=qi;
    Kre[obase+j]=kr*wsc; Kim[obase+j]=ki2*wsc;
  }
}

// ---------------- scores: 32t x 128s tiles, f split 4-ways into partials -------
__global__ __launch_bounds__(256) void k_scores(
  const float* __restrict__ Qre, const float* __restrict__ Qim,
  const float* __restrict__ Kre, const float* __restrict__ Kim,
  float* __restrict__ Pp)
{
  __shared__ float2 Ks[128*33];
  __shared__ float2 Qs[32*33];
  const int bid = blockIdx.x;
  const int b = bid>>7, h = (bid>>4)&7, tt = (bid>>2)&3, fq = bid&3;
  const int t = threadIdx.x;
  const int ts = t>>5, ss = t&31;
  float acc[4][4];
  #pragma unroll
  for(int i=0;i<4;i++)
    #pragma unroll
    for(int j=0;j<4;j++) acc[i][j]=0.f;
  const int fbase = fq*528;
  for(int ch=0; ch<16; ch++){
    const int fo = fbase + ch*33;
    __syncthreads();
    for(int idx=t; idx<4224; idx+=256){
      int s = idx/33, fl = idx - s*33;
      size_t off = ((size_t)((b*128+s)*8+h))*NT + fo + fl;
      Ks[idx] = make_float2(Kre[off], Kim[off]);
    }
    for(int idx=t; idx<1056; idx+=256){
      int tq = idx/33, fl = idx - tq*33;
      size_t off = ((size_t)((b*128+tt*32+tq)*8+h))*NT + fo + fl;
      Qs[idx] = make_float2(Qre[off], Qim[off]);
    }
    __syncthreads();
    for(int fl=0; fl<33; fl++){
      float2 qv[4], kv[4];
      #pragma unroll
      for(int i=0;i<4;i++) qv[i] = Qs[(ts*4+i)*33+fl];
      #pragma unroll
      for(int j=0;j<4;j++) kv[j] = Ks[(ss+32*j)*33+fl];
      #pragma unroll
      for(int i=0;i<4;i++)
        #pragma unroll
        for(int j=0;j<4;j++)
          acc[i][j] += qv[i].x*kv[j].x + qv[i].y*kv[j].y;
    }
  }
  #pragma unroll
  for(int i=0;i<4;i++){
    int tg = tt*32 + ts*4 + i;
    #pragma unroll
    for(int j=0;j<4;j++){
      int s = ss + 32*j;
      Pp[(size_t)fq*262144 + ((size_t)((b*8+h)*128+tg))*128 + s] = acc[i][j];
    }
  }
}

__global__ __launch_bounds__(64) void k_softmax(const float* __restrict__ Pp,
                                                float* __restrict__ P){
  const int row = blockIdx.x, tid = threadIdx.x;
  size_t o = (size_t)row*128;
  float v0=0.f, v1=0.f;
  #pragma unroll
  for(int q=0;q<4;q++){
    v0 += Pp[(size_t)q*262144 + o + tid];
    v1 += Pp[(size_t)q*262144 + o + tid + 64];
  }
  float mx = fmaxf(v0,v1);
  for(int off=32; off; off>>=1) mx = fmaxf(mx, __shfl_xor(mx, off));
  float e0 = expf(v0-mx), e1 = expf(v1-mx);
  float s = e0+e1;
  for(int off=32; off; off>>=1) s += __shfl_xor(s, off);
  float inv = 1.0f/s;
  P[o+tid] = e0*inv; P[o+tid+64] = e1*inv;
}

// PA^T[b][s][t] = alpha1[b*128+s] * sum_h psw*sv*P[b,h,t,s]
__global__ __launch_bounds__(256) void k_peff(const float* __restrict__ P,
   const float* __restrict__ p_sw, const float* __restrict__ kqv_sw,
   const float* __restrict__ a1, float* __restrict__ PAT)
{
  const int i = blockIdx.x*256 + threadIdx.x;
  const int b = i>>14, rem = i&16383;
  const int tch = rem>>7, s = rem&127;
  float acc=0.f;
  for(int hh=0; hh<8; hh++){
    float a = p_sw[hh]*kqv_sw[16+hh];
    acc += a * P[(((size_t)(b*8+hh))<<14) + rem];
  }
  PAT[((size_t)(b*128+s))*128 + tch] = acc * a1[b*128+s];
}

// pbeta[b*128+t] = sum_s (sum_h psw*sv*P) * beta1[b*128+s]
__global__ __launch_bounds__(128) void k_pbeta(const float* __restrict__ P,
   const float* __restrict__ p_sw, const float* __restrict__ kqv_sw,
   const float* __restrict__ b1, float* __restrict__ pbeta)
{
  __shared__ float red[128];
  const int bid = blockIdx.x;
  const int b = bid>>7, tch = bid&127;
  const int s = threadIdx.x;
  float acc=0.f;
  for(int hh=0; hh<8; hh++){
    float a = p_sw[hh]*kqv_sw[16+hh];
    acc += a * P[((size_t)((b*8+hh)*128+tch))*128 + s];
  }
  acc *= b1[b*128+s];
  red[s] = acc; __syncthreads();
  for(int off=64; off>0; off>>=1){
    if(s<off) red[s]+=red[s+off];
    __syncthreads();
  }
  if(s==0) pbeta[bid] = red[0];
}

// gather Xt at Omega_p (32 corner rows x 16 cols)
__global__ __launch_bounds__(256) void k_gather(
   const float* __restrict__ Xtr, const float* __restrict__ Xti,
   float* __restrict__ Xpr, float* __restrict__ Xpi)
{
  const int m = blockIdx.x, tid = threadIdx.x;
  for(int j=tid;j<512;j+=256){
    int r = j>>4, c = j&15;
    int row = (r<16)? r : 32+r;
    Xpr[m*512+j] = Xtr[m*NT + row*33 + c];
    Xpi[m*512+j] = Xti[m*NT + row*33 + c];
  }
}

__global__ __launch_bounds__(256) void k_zp(const float* __restrict__ P,
  const float* __restrict__ Xpr, const float* __restrict__ Xpi,
  float* __restrict__ Zr, float* __restrict__ Zi)
{
  __shared__ float Pt[2048];
  const int bid = blockIdx.x;
  const int b = bid>>6, o = (bid>>3)&7, ct = bid&7;
  const int tid = threadIdx.x;
  for(int idx=tid; idx<2048; idx+=256){
    int cl = idx>>7, s = idx&127;
    Pt[cl*128+s] = P[((size_t)((b*8+o)*128 + ct*16+cl))*128 + s];
  }
  __syncthreads();
  for(int it=0; it<2; it++){
    int j = tid + it*256;
    float ar[16], ai[16];
    #pragma unroll
    for(int c=0;c<16;c++){ ar[c]=0.f; ai[c]=0.f; }
    for(int s=0;s<128;s++){
      float xr = Xpr[(b*128+s)*512 + j];
      float xi = Xpi[(b*128+s)*512 + j];
      #pragma unroll
      for(int c=0;c<16;c++){
        float pv = Pt[c*128+s];
        ar[c] += pv*xr; ai[c] += pv*xi;
      }
    }
    #pragma unroll
    for(int c=0;c<16;c++){
      size_t off = ((size_t)((b*8+o)*128 + ct*16+c))*512 + j;
      Zr[off]=ar[c]; Zi[off]=ai[c];
    }
  }
}

// corner corrections -> Bc (512 modes per map)
__global__ __launch_bounds__(256) void k_corr(
  const float* __restrict__ Zr, const float* __restrict__ Zi,
  const float* __restrict__ kqv_wr, const float* __restrict__ kqv_wi,
  const float* __restrict__ kqv_bias, const float* __restrict__ kqv_sw, const float* __restrict__ kqv_sb,
  const float* __restrict__ p_wr, const float* __restrict__ p_wi,
  const float* __restrict__ p_bias, const float* __restrict__ p_sw, const float* __restrict__ p_sb,
  float* __restrict__ Bcr, float* __restrict__ Bci)
{
  const int m = blockIdx.x;
  const int b = m>>7, cix = m&127;
  const int tid = threadIdx.x;
  for(int j=tid; j<512; j+=256){
    int r = j>>4, c = j&15;
    int ky = (r<16)? r : 96+r;
    float accr=0.f, acci=0.f;
    int rp = -1;
    if(c==0){ int kyp = (128-ky)&127; rp = (kyp<16)? kyp : ((kyp>=112)? kyp-96 : -1); }
    for(int o=0;o<8;o++){
      size_t zoff = ((size_t)((b*8+o)*128 + cix))*512;
      float zr = Zr[zoff+j], zi = Zi[zoff+j];
      float cvr=0.f, cvi=0.f;
      bool inV = (c<8) && (ky<8 || ky>=120);
      if(inV){
        int vrow = (ky<8)? ky : 8+(ky-120);
        float wr = kqv_wr[((16+o)*16+vrow)*8+c], wi = kqv_wi[((16+o)*16+vrow)*8+c];
        cvr = wr*zr - wi*zi; cvi = wr*zi + wi*zr;
      }
      float ar = cvr, ai = cvi;
      if(c==0){
        float pvr=0.f, pvi=0.f;
        int kyp = (128-ky)&127;
        bool pInV = (kyp<8 || kyp>=120);
        if(pInV && rp>=0){
          int vrow = (kyp<8)? kyp : 8+(kyp-120);
          float zr2 = Zr[zoff + rp*16], zi2 = Zi[zoff + rp*16];
          float wr = kqv_wr[((16+o)*16+vrow)*8], wi = kqv_wi[((16+o)*16+vrow)*8];
          pvr = wr*zr2 - wi*zi2; pvi = wr*zi2 + wi*zr2;
        }
        ar = 0.5f*(cvr + pvr);
        ai = 0.5f*(cvi - pvi);
      }
      float sv = kqv_sw[16+o];
      float Dv = kqv_bias[16+o] + kqv_sb[16+o];
      float atr = sv*zr + ar + ((j==0)? Dv : 0.f);
      float ati = sv*zi + ai;
      float psw = p_sw[o];
      accr += psw*ar;  acci += psw*ai;
      float wpr = p_wr[(o*32+r)*16+c], wpi = p_wi[(o*32+r)*16+c];
      accr += wpr*atr - wpi*ati;
      acci += wpr*ati + wpi*atr;
      if(j==0) accr += psw*Dv;
    }
    if(j==0) accr += p_bias[0] + p_sb[0];
    Bcr[m*512+j] = accr; Bci[m*512+j] = acci;
  }
}

// ---------------- attn GEMM: y0g[b,t][p] = sum_s PA^T[s][t] * x[s][p] + pbeta --
__global__ __launch_bounds__(256) void k_attn_gemm(
  const float* __restrict__ PAT, const float* __restrict__ xin,
  const float* __restrict__ pbeta, float* __restrict__ y0g)
{
  __shared__ float PAs[32*65];
  __shared__ float Xs[32*256];
  const int bid = blockIdx.x;
  const int b = bid>>7, ct = (bid>>6)&1, pt = bid&63;
  const int t = threadIdx.x;
  const int tc = t>>6, tp = t&63;
  float4 acc[16];
  #pragma unroll
  for(int k=0;k<16;k++) acc[k] = make_float4(0.f,0.f,0.f,0.f);
  for(int sc4=0; sc4<4; sc4++){
    __syncthreads();
    for(int idx=t; idx<2048; idx+=256){
      int sl = idx>>6, cl = idx&63;
      PAs[sl*65+cl] = PAT[((size_t)(b*128 + sc4*32+sl))*128 + ct*64+cl];
    }
    for(int q=t; q<2048; q+=256){
      int sl = q>>6, p4 = q&63;
      ((float4*)Xs)[sl*64+p4] =
        ((const float4*)xin)[((size_t)(b*128 + sc4*32+sl))*4096 + pt*64 + p4];
    }
    __syncthreads();
    for(int sl=0; sl<32; sl++){
      float4 xv = ((const float4*)Xs)[sl*64+tp];
      #pragma unroll
      for(int k=0;k<16;k++){
        float pa = PAs[sl*65 + tc*16+k];
        acc[k].x += pa*xv.x; acc[k].y += pa*xv.y;
        acc[k].z += pa*xv.z; acc[k].w += pa*xv.w;
      }
    }
  }
  #pragma unroll
  for(int k=0;k<16;k++){
    int c = ct*64 + tc*16 + k;
    float pb = pbeta[b*128+c];
    float4 o = acc[k];
    o.x += pb; o.y += pb; o.z += pb; o.w += pb;
    ((float4*)y0g)[((size_t)(b*128+c))*4096 + pt*64 + tp] = o;
  }
}

// ---------------- epi0: attn = IN(y0g + cinv(Bc) + x)*aw+ab ; emit alpha2/beta2
__global__ __launch_bounds__(256) void k_epi0(
  const float* __restrict__ y0g, const float* __restrict__ xin,
  const float* __restrict__ Bcr, const float* __restrict__ Bci,
  const float2* __restrict__ CS,
  const float* __restrict__ awp, const float* __restrict__ abp,
  const float* __restrict__ n2w, const float* __restrict__ n2b,
  float* __restrict__ attn, float* __restrict__ a2, float* __restrict__ b2)
{
  __shared__ float2 Bcl[512];
  __shared__ float2 V[128*17];
  __shared__ float red[512];
  const int m = blockIdx.x, t = threadIdx.x;
  for(int j=t;j<512;j+=256) Bcl[j] = make_float2(Bcr[m*512+j], Bci[m*512+j]);
  __syncthreads();
  #pragma unroll
  for(int k=0;k<8;k++){
    int idx = t + 256*k;
    int mm = idx>>4, c = idx&15;
    float vr=0.f, vi=0.f;
    for(int r=0;r<32;r++){
      int ky = (r<16)? r : 96+r;
      float2 bc = Bcl[r*16+c];
      float2 cs = CS[128 + ((ky*mm)&127)];
      vr += bc.x*cs.x - bc.y*cs.y;
      vi += bc.x*cs.y + bc.y*cs.x;
    }
    float w = (c==0)?1.0f:2.0f;
    V[mm*17+c] = make_float2(vr*w, vi*w);
  }
  __syncthreads();
  const float4* x4 = (const float4*)(xin + (size_t)m*16384);
  const float4* g4 = (const float4*)(y0g + (size_t)m*16384);
  float s1=0.f, s2=0.f;
  for(int k=0;k<16;k++){
    int q = t + 256*k;
    int mm = q>>5, n0 = (q&31)*4;
    float4 xv = x4[q], gv = g4[q];
    float vv[4] = {xv.x+gv.x, xv.y+gv.y, xv.z+gv.z, xv.w+gv.w};
    #pragma unroll
    for(int d=0;d<4;d++){
      int n = n0+d;
      float cv = 0.f;
      #pragma unroll
      for(int c=0;c<16;c++){
        float2 v2 = V[mm*17+c];
        float2 cs = CS[c*128+n];
        cv += v2.x*cs.x - v2.y*cs.y;
      }
      float v = vv[d] + cv;
      s1 += v; s2 += v*v;
    }
  }
  blockReduce2(s1,s2,red);
  float mu = s1*(1.0f/16384.0f);
  float var = s2*(1.0f/16384.0f)-mu*mu;
  float rs = rsqrtf(var+1e-5f);
  float aw = awp[0], ab = abp[0];
  float4* at4 = (float4*)(attn + (size_t)m*16384);
  for(int k=0;k<16;k++){
    int q = t + 256*k;
    int mm = q>>5, n0 = (q&31)*4;
    float4 xv = x4[q], gv = g4[q];
    float vv[4] = {xv.x+gv.x, xv.y+gv.y, xv.z+gv.z, xv.w+gv.w};
    float4 ov;
    float* op = &ov.x;
    #pragma unroll
    for(int d=0;d<4;d++){
      int n = n0+d;
      float cv = 0.f;
      #pragma unroll
      for(int c=0;c<16;c++){
        float2 v2 = V[mm*17+c];
        float2 cs = CS[c*128+n];
        cv += v2.x*cs.x - v2.y*cs.y;
      }
      op[d] = (vv[d] + cv - mu)*rs*aw + ab;
    }
    at4[q] = ov;
  }
  if(t==0){
    float va = aw*aw*var/(var+1e-5f);
    float al = n2w[m&3]*rsqrtf(va+1e-5f);
    a2[m] = al; b2[m] = n2b[m&3] - ab*al;
  }
}

// ---------------- corner rfft2 (32 rows x 16 cols) of a spatial map ------------
__global__ __launch_bounds__(256) void k_rfft_corner(
  const float* __restrict__ z, const float* __restrict__ alpha,
  const float* __restrict__ dcv, const int dcmask,
  const float2* __restrict__ CS, float2* __restrict__ Hc)
{
  __shared__ float zl[32*129];
  __shared__ float2 Rc[128*17];
  const int m = blockIdx.x, t = threadIdx.x;
  const int yl = t&31, cg = t>>5;
  for(int yc=0; yc<4; yc++){
    __syncthreads();
    {
      const float4* zp4 = (const float4*)(z + (size_t)m*16384 + yc*4096);
      for(int i4=t;i4<1024;i4+=256){
        float4 v = zp4[i4];
        int y = i4>>5, n = (i4&31)*4;
        zl[y*129+n]=v.x; zl[y*129+n+1]=v.y; zl[y*129+n+2]=v.z; zl[y*129+n+3]=v.w;
      }
    }
    __syncthreads();
    #pragma unroll
    for(int k=0;k<2;k++){
      int c = cg + 8*k;
      float ar=0.f, ai=0.f;
      for(int n=0;n<128;n++){
        float zv = zl[yl*129+n];
        float2 cs = CS[c*128+n];
        ar += zv*cs.x; ai -= zv*cs.y;
      }
      Rc[(yc*32+yl)*17 + c] = make_float2(ar, ai);
    }
  }
  __syncthreads();
  const float sc = (alpha ? alpha[m] : 1.0f) * (1.0f/16384.0f);
  #pragma unroll
  for(int k=0;k<2;k++){
    int idx = t + 256*k;
    int r = idx>>4, c = idx&15;
    int ky = (r<16)? r : 96+r;
    float hr=0.f, hi=0.f;
    for(int y=0;y<128;y++){
      float2 Rv = Rc[y*17+c];
      float2 cs = CS[128 + ((ky*y)&127)];
      hr += Rv.x*cs.x + Rv.y*cs.y;
      hi += Rv.y*cs.x - Rv.x*cs.y;
    }
    float2 o = make_float2(hr*sc, hi*sc);
    if(idx==0 && dcv) o = make_float2(dcv[m&dcmask], 0.f);
    Hc[m*512+idx] = o;
  }
}

// ---------------- mixer spectral: S = sum_i w.Hc ; IN in freq -> Sn ------------
__global__ __launch_bounds__(256) void k_mixc(
  const float2* __restrict__ Hc,
  const float* __restrict__ wr0, const float* __restrict__ wi0,
  float2* __restrict__ Sn)
{
  __shared__ float2 Sl[512];
  __shared__ float red[512];
  const int m = blockIdx.x;
  const int g = m>>2, o = m&3;
  const int t = threadIdx.x;
  for(int j=t;j<512;j+=256){
    int r = j>>4, c = j&15;
    float ar=0.f, ai=0.f;
    for(int i2=0;i2<4;i2++){
      float2 h = Hc[(g*4+i2)*512 + j];
      float wr = wr0[((i2*4+o)*32+r)*16+c], wi = wi0[((i2*4+o)*32+r)*16+c];
      ar += wr*h.x - wi*h.y; ai += wr*h.y + wi*h.x;
    }
    Sl[j] = make_float2(ar, ai);
  }
  __syncthreads();
  float vs=0.f, dummy=0.f;
  for(int j=t;j<512;j+=256){
    int c=j&15;
    if(c>=1) vs += 2.0f*(Sl[j].x*Sl[j].x + Sl[j].y*Sl[j].y);
  }
  if(t<32){
    int ky = (t<16)? (t+1) : (96+t);
    float ar=0.f, ai=0.f;
    if(ky<16){ ar=Sl[ky*16].x; ai=Sl[ky*16].y; }
    else if(ky>=112){ int r=ky-96; ar=Sl[r*16].x; ai=Sl[r*16].y; }
    int kyp = 128-ky;
    float br2=0.f, bi2=0.f;
    if(kyp<16){ br2=Sl[kyp*16].x; bi2=Sl[kyp*16].y; }
    else if(kyp>=112){ int r=kyp-96; br2=Sl[r*16].x; bi2=Sl[r*16].y; }
    float pr = 0.5f*(ar+br2), pi = 0.5f*(ai-bi2);
    vs += pr*pr + pi*pi;
  }
  blockReduce2(vs, dummy, red);
  float rs2 = rsqrtf(vs + 1e-5f);
  for(int j=t;j<512;j+=256){
    float2 s = Sl[j];
    if(j==0) Sn[m*512+j] = make_float2(0.f,0.f);
    else     Sn[m*512+j] = make_float2(s.x*rs2, s.y*rs2);
  }
}

// ---------------- mixer inverse: out = [gelu]( sum_i cw*in_i + cb + cinv(Sn) ) -
__global__ __launch_bounds__(256) void k_mixinv(
  const float2* __restrict__ Sn, const float* __restrict__ inmaps,
  const float* __restrict__ a2, const float* __restrict__ b2,
  const float* __restrict__ msw, const float* __restrict__ msb,
  const float2* __restrict__ CS, const int dogelu, float* __restrict__ outp)
{
  __shared__ float2 Sl[512];
  __shared__ float2 V[128*17];
  const int m = blockIdx.x;
  const int g = m>>2, o = m&3;
  const int t = threadIdx.x;
  float cw[4]; float cb = msb[o];
  #pragma unroll
  for(int i=0;i<4;i++){
    float al = a2 ? a2[g*4+i] : 1.0f;
    float be = b2 ? b2[g*4+i] : 0.0f;
    float sw = msw[o*4+i];
    cw[i] = sw*al; cb += sw*be;
  }
  for(int j=t;j<512;j+=256) Sl[j] = Sn[m*512+j];
  __syncthreads();
  #pragma unroll
  for(int k=0;k<8;k++){
    int idx = t + 256*k;
    int mm = idx>>4, c = idx&15;
    float vr=0.f, vi=0.f;
    for(int r=0;r<32;r++){
      int ky = (r<16)? r : 96+r;
      float2 bc = Sl[r*16+c];
      float2 cs = CS[128 + ((ky*mm)&127)];
      vr += bc.x*cs.x - bc.y*cs.y;
      vi += bc.x*cs.y + bc.y*cs.x;
    }
    float w = (c==0)?1.0f:2.0f;
    V[mm*17+c] = make_float2(vr*w, vi*w);
  }
  __syncthreads();
  const float4* in4 = (const float4*)(inmaps + (size_t)(g*4)*16384);
  float4* o4 = (float4*)(outp + (size_t)m*16384);
  for(int k=0;k<16;k++){
    int q = t + 256*k;
    int mm = q>>5, n0 = (q&31)*4;
    float4 v0 = in4[q], v1 = in4[4096+q], v2 = in4[8192+q], v3 = in4[12288+q];
    float4 ov;
    float* op = &ov.x;
    float base[4] = {
      cb + cw[0]*v0.x + cw[1]*v1.x + cw[2]*v2.x + cw[3]*v3.x,
      cb + cw[0]*v0.y + cw[1]*v1.y + cw[2]*v2.y + cw[3]*v3.y,
      cb + cw[0]*v0.z + cw[1]*v1.z + cw[2]*v2.z + cw[3]*v3.z,
      cb + cw[0]*v0.w + cw[1]*v1.w + cw[2]*v2.w + cw[3]*v3.w };
    #pragma unroll
    for(int d=0;d<4;d++){
      int n = n0+d;
      float cv = 0.f;
      #pragma unroll
      for(int c=0;c<16;c++){
        float2 vv = V[mm*17+c];
        float2 cs = CS[c*128+n];
        cv += vv.x*cs.x - vv.y*cs.y;
      }
      float val = base[d] + cv;
      if(dogelu) val = 0.5f*val*(1.0f+erff(val*0.70710678118f));
      op[d] = val;
    }
    o4[q] = ov;
  }
}

// ---------------- final: out = IN(h2)*mw+mb + attn -----------------------------
__global__ __launch_bounds__(256) void k_epi2(
    const float* __restrict__ h2, const float* __restrict__ attn,
    const float* __restrict__ mw, const float* __restrict__ mbv,
    float* __restrict__ outp)
{
  __shared__ float red[512];
  const int m = blockIdx.x, t = threadIdx.x;
  const float4* h4 = (const float4*)(h2 + (size_t)m*16384);
  const float4* a4 = (const float4*)(attn + (size_t)m*16384);
  float4* o4 = (float4*)(outp + (size_t)m*16384);
  float s1=0.f, s2=0.f;
  for(int i=t;i<4096;i+=256){
    float4 v = h4[i];
    s1 += v.x+v.y+v.z+v.w;
    s2 += v.x*v.x+v.y*v.y+v.z*v.z+v.w*v.w;
  }
  blockReduce2(s1,s2,red);
  float mu = s1*(1.0f/16384.0f);
  float var = s2*(1.0f/16384.0f)-mu*mu;
  float rs = rsqrtf(var+1e-5f);
  float w = mw[m&3], b = mbv[m&3];
  for(int i=t;i<4096;i+=256){
    float4 v = h4[i], av = a4[i];
    float4 ov;
    ov.x = (v.x-mu)*rs*w + b + av.x;
    ov.y = (v.y-mu)*rs*w + b + av.y;
    ov.z = (v.z-mu)*rs*w + b + av.z;
    ov.w = (v.w-mu)*rs*w + b + av.w;
    o4[i] = ov;
  }
}

extern "C" void kernel_launch(void* const* d_in, const int* in_sizes, int n_in,
                              void* d_out, int out_size, void* d_ws, size_t ws_size,
                              hipStream_t stream)
{
  const float* x        = (const float*)d_in[0];
  const float* norm1_w  = (const float*)d_in[1];
  const float* norm1_b  = (const float*)d_in[2];
  const float* kqv_wr   = (const float*)d_in[3];
  const float* kqv_wi   = (const float*)d_in[4];
  const float* kqv_bias = (const float*)d_in[5];
  const float* kqv_sw   = (const float*)d_in[6];
  const float* kqv_sb   = (const float*)d_in[7];
  const float* p_wr     = (const float*)d_in[8];
  const float* p_wi     = (const float*)d_in[9];
  const float* p_bias   = (const float*)d_in[10];
  const float* p_sw     = (const float*)d_in[11];
  const float* p_sb     = (const float*)d_in[12];
  const float* attn_norm_w = (const float*)d_in[13];
  const float* attn_norm_b = (const float*)d_in[14];
  const float* norm2_w  = (const float*)d_in[15];
  const float* norm2_b  = (const float*)d_in[16];
  const float* mix_wr   = (const float*)d_in[17];
  const float* mix_wi   = (const float*)d_in[18];
  // mix_bias (d_in[19]) only shifts the spectral mean which IN removes -> unused
  const float* mix_sw   = (const float*)d_in[20];
  const float* mix_sb   = (const float*)d_in[21];
  const float* mon_w    = (const float*)d_in[22];
  const float* mon_b    = (const float*)d_in[23];
  float* out = (float*)d_out;

  const size_t NEED = (size_t)27624704 * sizeof(float);
  if(ws_size < NEED) return;

  float* ws = (float*)d_ws;
  size_t off = 0;
  float2* CS  = (float2*)(ws + off); off += 32768;
  float* a1   = ws + off; off += 256;
  float* b1   = ws + off; off += 256;
  float* a2   = ws + off; off += 256;
  float* b2   = ws + off; off += 256;
  float* pbeta= ws + off; off += 256;
  float* Xtr  = ws + off; off += 540672;
  float* Xti  = ws + off; off += 540672;
  float* pool = ws + off; off += 17301504;
  float* Pp   = ws + off; off += 1048576;
  float* P    = ws + off; off += 262144;
  float* PAT  = ws + off; off += 32768;
  float* Xpr  = ws + off; off += 131072;
  float* Xpi  = ws + off; off += 131072;
  float* Zr   = ws + off; off += 1048576;
  float* Zi   = ws + off; off += 1048576;
  float* Bcr  = ws + off; off += 131072;
  float* Bci  = ws + off; off += 131072;
  float* attn = ws + off; off += 4194304;
  float2* Hc  = (float2*)(ws + off); off += 524288;
  float2* Sn  = (float2*)(ws + off); off += 524288;

  // pool slots (4 x 4325376)
  float* R1r = pool;                  // dead after k_p2
  float* R1i = pool + 1081344;
  float* Qre = pool;
  float* Qim = pool + 4325376;
  float* Kre = pool + 8650752;
  float* Kim = pool + 12976128;
  float* y0g = pool;                  // after scores (Q/K dead)
  float* h1  = pool + 4325376;
  float* h2  = pool + 8650752;

  k_tables<<<dim3(128), dim3(128), 0, stream>>>(CS);
  k_instats<<<dim3(256), dim3(256), 0, stream>>>(x, norm1_w, norm1_b, a1, b1);
  k_p1<<<dim3(1024), dim3(256), 0, stream>>>(x, R1r, R1i, CS);
  k_p2<<<dim3(256), dim3(320), 0, stream>>>(R1r, R1i, CS, a1, norm1_b, Xtr, Xti);
  k_build_qk<<<dim3(2048), dim3(256), 0, stream>>>(Xtr, Xti, kqv_wr, kqv_wi, kqv_bias,
                                                   kqv_sw, kqv_sb, Qre, Qim, Kre, Kim);
  k_scores<<<dim3(256), dim3(256), 0, stream>>>(Qre, Qim, Kre, Kim, Pp);
  k_softmax<<<dim3(2048), dim3(64), 0, stream>>>(Pp, P);
  k_peff<<<dim3(128), dim3(256), 0, stream>>>(P, p_sw, kqv_sw, a1, PAT);
  k_pbeta<<<dim3(256), dim3(128), 0, stream>>>(P, p_sw, kqv_sw, b1, pbeta);
  k_gather<<<dim3(256), dim3(256), 0, stream>>>(Xtr, Xti, Xpr, Xpi);
  k_zp<<<dim3(128), dim3(256), 0, stream>>>(P, Xpr, Xpi, Zr, Zi);
  k_corr<<<dim3(256), dim3(256), 0, stream>>>(Zr, Zi, kqv_wr, kqv_wi, kqv_bias, kqv_sw, kqv_sb,
                                              p_wr, p_wi, p_bias, p_sw, p_sb, Bcr, Bci);
  k_attn_gemm<<<dim3(256), dim3(256), 0, stream>>>(PAT, x, pbeta, y0g);
  k_epi0<<<dim3(256), dim3(256), 0, stream>>>(y0g, x, Bcr, Bci, CS, attn_norm_w, attn_norm_b,
                                              norm2_w, norm2_b, attn, a2, b2);
  // mixer layer 1
  k_rfft_corner<<<dim3(256), dim3(256), 0, stream>>>(attn, a2, norm2_b, 3, CS, Hc);
  k_mixc<<<dim3(256), dim3(256), 0, stream>>>(Hc, mix_wr, mix_wi, Sn);
  k_mixinv<<<dim3(256), dim3(256), 0, stream>>>(Sn, attn, a2, b2, mix_sw, mix_sb, CS, 1, h1);
  // mixer layer 2
  k_rfft_corner<<<dim3(256), dim3(256), 0, stream>>>(h1, (const float*)nullptr,
                                                     (const float*)nullptr, 0, CS, Hc);
  k_mixc<<<dim3(256), dim3(256), 0, stream>>>(Hc, mix_wr+8192, mix_wi+8192, Sn);
  k_mixinv<<<dim3(256), dim3(256), 0, stream>>>(Sn, h1, (const float*)nullptr, (const float*)nullptr,
                                                mix_sw+16, mix_sb+4, CS, 0, h2);
  k_epi2<<<dim3(256), dim3(256), 0, stream>>>(h2, attn, mon_w, mon_b, out);
}

// Round 4
// 472.932 us; speedup vs baseline: 15.7526x; 1.2604x over previous
//
#include <hip/hip_runtime.h>
#include <math.h>

// TNO block, round 4: occupancy/GEMM-shape pass.
//  - scores = flat-real SGEMM (Parseval), 64x64 tiles, grid 1024
//  - zp, attn_gemm re-tiled for >=512-block grids, broadcast-weight inner loops
//  - p2 704-thread divergence-free
// Spectra: forward-normalized, x[y][n] = sum A e^{+2pi i(ky y+kx n)/128}.

#define NT 2112   // 64*33 truncated spectrum per map

__device__ __forceinline__ void blockReduce2(float& a, float& b, float* red){
  int tid = threadIdx.x;
  red[tid] = a; red[256+tid] = b;
  __syncthreads();
  for(int off=128; off>0; off>>=1){
    if(tid<off){ red[tid]+=red[tid+off]; red[256+tid]+=red[256+tid+off]; }
    __syncthreads();
  }
  a = red[0]; b = red[256];
  __syncthreads();
}

// ---------------- twiddle table: CS[a*128+b] = (cos,sin)(2pi a b/128) ----------
__global__ void k_tables(float2* __restrict__ CS){
  int a = blockIdx.x, b = threadIdx.x;
  int p = (a*b)&127;
  float t = (float)p * (1.0f/64.0f);
  CS[a*128+b] = make_float2(cospif(t), sinpif(t));
}

// ---------------- per-map IN stats of x: alpha1 = w*rs, beta1 = b - mu*alpha ---
__global__ __launch_bounds__(256) void k_instats(
    const float* __restrict__ xin, const float* __restrict__ n1w,
    const float* __restrict__ n1b, float* __restrict__ a1, float* __restrict__ b1)
{
  __shared__ float red[512];
  const int m = blockIdx.x, t = threadIdx.x;
  const float* xp = xin + (size_t)m*16384;
  float s1=0.f, s2=0.f;
  for(int i=t;i<4096;i+=256){
    float4 v = ((const float4*)xp)[i];
    s1 += v.x+v.y+v.z+v.w;
    s2 += v.x*v.x+v.y*v.y+v.z*v.z+v.w*v.w;
  }
  blockReduce2(s1,s2,red);
  if(t==0){
    float mu = s1*(1.0f/16384.0f);
    float var = s2*(1.0f/16384.0f)-mu*mu;
    float a = n1w[0]*rsqrtf(var+1e-5f);
    a1[m] = a; b1[m] = n1b[0] - mu*a;
  }
}

// ---------------- k_p1: x-dim partial DFT (33 cols): R[y][c] -------------------
__global__ __launch_bounds__(256) void k_p1(
    const float* __restrict__ xin, float* __restrict__ R1r, float* __restrict__ R1i,
    const float2* __restrict__ CS)
{
  __shared__ float xl[32*129];
  __shared__ float2 csl[4224];
  const int bid = blockIdx.x;
  const int m = bid>>2, yt = bid&3;
  const int t = threadIdx.x;
  for(int i=t;i<4224;i+=256) csl[i] = CS[i];
  {
    const float4* xp4 = (const float4*)(xin + (size_t)m*16384 + yt*4096);
    for(int i4=t;i4<1024;i4+=256){
      float4 v = xp4[i4];
      int y = i4>>5, n = (i4&31)*4;
      xl[y*129+n]=v.x; xl[y*129+n+1]=v.y; xl[y*129+n+2]=v.z; xl[y*129+n+3]=v.w;
    }
  }
  __syncthreads();
  const int yl = t&31, cg = t>>5;
  const int nc = (cg==0)?5:4;
  float ar[5]={0,0,0,0,0}, ai[5]={0,0,0,0,0};
  for(int n=0;n<128;n++){
    float xv = xl[yl*129+n];
    #pragma unroll
    for(int k=0;k<5;k++){
      if(k<nc){
        float2 cs = csl[(cg+8*k)*128+n];
        ar[k] += xv*cs.x;
        ai[k] -= xv*cs.y;
      }
    }
  }
  __syncthreads();
  #pragma unroll
  for(int k=0;k<5;k++){
    if(k<nc){
      int c = cg+8*k;
      xl[yl*33+c] = ar[k];
      xl[1056 + yl*33+c] = ai[k];
    }
  }
  __syncthreads();
  const int gb = m*4224 + yt*1056;
  for(int idx=t; idx<2112; idx+=256){
    if(idx<1056) R1r[gb+idx] = xl[idx];
    else         R1i[gb+idx-1056] = xl[idx];
  }
}

// ---------------- k_p2: y-dim DFT -> Xt[r*33+c], r<32: ky=r else ky=r+64 -------
__global__ __launch_bounds__(704) void k_p2(
    const float* __restrict__ R1r, const float* __restrict__ R1i,
    const float2* __restrict__ CS, const float* __restrict__ a1,
    const float* __restrict__ n1b,
    float* __restrict__ Xtr, float* __restrict__ Xti)
{
  __shared__ float2 Rl[128*34];
  const int m = blockIdx.x, t = threadIdx.x;
  for(int idx=t; idx<4224; idx+=704){
    int y = idx/33, c = idx - y*33;
    Rl[y*34+c] = make_float2(R1r[m*4224+idx], R1i[m*4224+idx]);
  }
  __syncthreads();
  const float sc = a1[m]*(1.0f/16384.0f);
  const int r = t&63;
  const int ky = (r<32)? r : r+64;
  #pragma unroll
  for(int k=0;k<3;k++){
    int c = (t>>6) + 11*k;
    float ar=0.f, ai=0.f;
    for(int y=0;y<128;y++){
      float2 Rv = Rl[y*34+c];            // wave-uniform broadcast
      float2 cs = CS[128 + ((ky*y)&127)];
      ar += Rv.x*cs.x + Rv.y*cs.y;
      ai += Rv.y*cs.x - Rv.x*cs.y;
    }
    int j = r*33 + c;
    float vr = ar*sc, vi = ai*sc;
    if(j==0){ vr = n1b[0]; vi = 0.f; }
    Xtr[m*NT+j] = vr; Xti[m*NT+j] = vi;
  }
}

// ---------------- K/Q spectra on the 64-grid (trunc + corners + Pi proj) -------
__global__ __launch_bounds__(256) void k_build_qk(
  const float* __restrict__ Xtr, const float* __restrict__ Xti,
  const float* __restrict__ kqv_wr, const float* __restrict__ kqv_wi,
  const float* __restrict__ kqv_bias, const float* __restrict__ kqv_sw, const float* __restrict__ kqv_sb,
  float2* __restrict__ Qc, float2* __restrict__ Kc)
{
  __shared__ float Tre[2112], Tim[2112];
  __shared__ float Qr[2112], Qi[2112], Kr[2112], Ki[2112];
  const int bid = blockIdx.x;
  const int m = bid>>3, o = bid&7;
  const int tid = threadIdx.x;
  for(int j=tid;j<2112;j+=256){
    Tre[j] = Xtr[m*NT+j];
    Tim[j] = Xti[m*NT+j];
  }
  __syncthreads();
  const float swK = kqv_sw[o];
  const float swQ = kqv_sw[8+o];
  for(int j=tid;j<2112;j+=256){
    int r = j/33, c = j - r*33;
    float tr = Tre[j], ti = Tim[j];
    float kr = swK*tr, ki2 = swK*ti;
    float qr = swQ*tr, qi = swQ*ti;
    if(c<8){
      int wrow = (r<8)? r : ((r>=56)? 8+(r-56) : -1);
      if(wrow>=0){
        float wkr = kqv_wr[(o*16+wrow)*8+c],      wki = kqv_wi[(o*16+wrow)*8+c];
        kr += wkr*tr - wki*ti; ki2 += wkr*ti + wki*tr;
        float wqr = kqv_wr[((8+o)*16+wrow)*8+c],  wqi = kqv_wi[((8+o)*16+wrow)*8+c];
        qr += wqr*tr - wqi*ti; qi += wqr*ti + wqi*tr;
      }
    }
    if(j==0){
      kr += kqv_bias[o]   + kqv_sb[o];
      qr += kqv_bias[8+o] + kqv_sb[8+o];
    }
    Kr[j]=kr; Ki[j]=ki2; Qr[j]=qr; Qi[j]=qi;
  }
  __syncthreads();
  const size_t obase = ((size_t)(m*8+o))*NT;
  for(int j=tid;j<2112;j+=256){
    int r = j/33, c = j - r*33;
    float kr=Kr[j], ki2=Ki[j], qr=Qr[j], qi=Qi[j];
    float wsc = 128.0f;
    if(c==0 || c==32){
      int pj = ((64-r)&63)*33 + c;
      kr = 0.5f*(Kr[j]+Kr[pj]); ki2 = 0.5f*(Ki[j]-Ki[pj]);
      qr = 0.5f*(Qr[j]+Qr[pj]); qi  = 0.5f*(Qi[j]-Qi[pj]);
      wsc = 64.0f;
    }
    Qc[obase+j] = make_float2(qr, qi);
    Kc[obase+j] = make_float2(kr*wsc, ki2*wsc);
  }
}

// ---------------- scores SGEMM: S[t,s] = sum_{4224 reals} Q*K, 16 f-partials ---
__global__ __launch_bounds__(256) void k_scores(
  const float2* __restrict__ Qc, const float2* __restrict__ Kc,
  float* __restrict__ Pp)
{
  __shared__ float Qs[64*52];
  __shared__ float Ks[64*52];
  const int bid = blockIdx.x;
  const int fq = bid&15, st = (bid>>4)&1, tt = (bid>>5)&1, h = (bid>>6)&7, b = bid>>9;
  const int t = threadIdx.x;
  const int tg = t>>4, sg = t&15;
  const int t0 = tt*64, s0 = st*64;
  const int f2base = fq*132;
  float acc[4][4];
  #pragma unroll
  for(int i=0;i<4;i++)
    #pragma unroll
    for(int j=0;j<4;j++) acc[i][j]=0.f;
  for(int sub=0; sub<6; sub++){
    __syncthreads();
    const int fo = f2base + sub*22;
    for(int idx=t; idx<1408; idx+=256){
      int rl = idx/22, f2 = idx - rl*22;
      float2 q = Qc[((size_t)((b*128 + t0+rl)*8+h))*NT + fo + f2];
      ((float2*)(Qs + rl*52))[f2] = q;
      float2 kk = Kc[((size_t)((b*128 + s0+rl)*8+h))*NT + fo + f2];
      ((float2*)(Ks + rl*52))[f2] = kk;
    }
    __syncthreads();
    #pragma unroll
    for(int f4=0; f4<11; f4++){
      float4 qv[4], kv[4];
      #pragma unroll
      for(int i=0;i<4;i++) qv[i] = *(const float4*)&Qs[(tg+16*i)*52 + f4*4];
      #pragma unroll
      for(int j=0;j<4;j++) kv[j] = *(const float4*)&Ks[(sg+16*j)*52 + f4*4];
      #pragma unroll
      for(int i=0;i<4;i++)
        #pragma unroll
        for(int j=0;j<4;j++)
          acc[i][j] += qv[i].x*kv[j].x + qv[i].y*kv[j].y
                     + qv[i].z*kv[j].z + qv[i].w*kv[j].w;
    }
  }
  #pragma unroll
  for(int i=0;i<4;i++){
    int tg2 = t0 + tg + 16*i;
    #pragma unroll
    for(int j=0;j<4;j++){
      int s = s0 + sg + 16*j;
      Pp[(size_t)fq*262144 + ((size_t)((b*8+h)*128+tg2))*128 + s] = acc[i][j];
    }
  }
}

__global__ __launch_bounds__(64) void k_softmax(const float* __restrict__ Pp,
                                                float* __restrict__ P){
  const int row = blockIdx.x, tid = threadIdx.x;
  size_t o = (size_t)row*128;
  float v0=0.f, v1=0.f;
  #pragma unroll
  for(int q=0;q<16;q++){
    v0 += Pp[(size_t)q*262144 + o + tid];
    v1 += Pp[(size_t)q*262144 + o + tid + 64];
  }
  float mx = fmaxf(v0,v1);
  for(int off=32; off; off>>=1) mx = fmaxf(mx, __shfl_xor(mx, off));
  float e0 = expf(v0-mx), e1 = expf(v1-mx);
  float s = e0+e1;
  for(int off=32; off; off>>=1) s += __shfl_xor(s, off);
  float inv = 1.0f/s;
  P[o+tid] = e0*inv; P[o+tid+64] = e1*inv;
}

// PA^T[b][s][t] = alpha1[b*128+s] * sum_h psw*sv*P[b,h,t,s]
__global__ __launch_bounds__(256) void k_peff(const float* __restrict__ P,
   const float* __restrict__ p_sw, const float* __restrict__ kqv_sw,
   const float* __restrict__ a1, float* __restrict__ PAT)
{
  const int i = blockIdx.x*256 + threadIdx.x;
  const int b = i>>14, rem = i&16383;
  const int tch = rem>>7, s = rem&127;
  float acc=0.f;
  for(int hh=0; hh<8; hh++){
    float a = p_sw[hh]*kqv_sw[16+hh];
    acc += a * P[(((size_t)(b*8+hh))<<14) + rem];
  }
  PAT[((size_t)(b*128+s))*128 + tch] = acc * a1[b*128+s];
}

// pbeta[b*128+t] = sum_s (sum_h psw*sv*P) * beta1[b*128+s]
__global__ __launch_bounds__(128) void k_pbeta(const float* __restrict__ P,
   const float* __restrict__ p_sw, const float* __restrict__ kqv_sw,
   const float* __restrict__ b1, float* __restrict__ pbeta)
{
  __shared__ float red[128];
  const int bid = blockIdx.x;
  const int b = bid>>7, tch = bid&127;
  const int s = threadIdx.x;
  float acc=0.f;
  for(int hh=0; hh<8; hh++){
    float a = p_sw[hh]*kqv_sw[16+hh];
    acc += a * P[((size_t)((b*8+hh)*128+tch))*128 + s];
  }
  acc *= b1[b*128+s];
  red[s] = acc; __syncthreads();
  for(int off=64; off>0; off>>=1){
    if(s<off) red[s]+=red[s+off];
    __syncthreads();
  }
  if(s==0) pbeta[bid] = red[0];
}

// gather Xt at Omega_p (32 corner rows x 16 cols) -> interleaved complex
__global__ __launch_bounds__(256) void k_gather(
   const float* __restrict__ Xtr, const float* __restrict__ Xti,
   float2* __restrict__ Xp)
{
  const int m = blockIdx.x, tid = threadIdx.x;
  for(int j=tid;j<512;j+=256){
    int r = j>>4, c = j&15;
    int row = (r<16)? r : 32+r;
    Xp[m*512+j] = make_float2(Xtr[m*NT + row*33 + c], Xti[m*NT + row*33 + c]);
  }
}

// Zc[b,o,c][j complex] = sum_s P[b,o,c,s] * Xp[b,s][j] ; GEMM-tiled, grid 512
__global__ __launch_bounds__(256) void k_zp(const float* __restrict__ P,
  const float* __restrict__ Xp, float* __restrict__ Zc)
{
  __shared__ float Pt[32*17];
  __shared__ float Xs[32*256];
  const int bid = blockIdx.x;
  const int b = bid>>8, o = (bid>>5)&7, ct = (bid>>2)&7, jt = bid&3;
  const int t = threadIdx.x;
  const int tc = t>>6, tj = t&63;
  const int c0 = ct*16;
  float4 acc[4];
  #pragma unroll
  for(int k=0;k<4;k++) acc[k] = make_float4(0.f,0.f,0.f,0.f);
  for(int scn=0; scn<4; scn++){
    __syncthreads();
    for(int idx=t; idx<512; idx+=256){
      int sl = idx&31, cl = idx>>5;
      Pt[sl*17+cl] = P[((size_t)((b*8+o)*128 + c0+cl))*128 + scn*32+sl];
    }
    for(int q=t; q<2048; q+=256){
      int sl = q>>6, p4 = q&63;
      ((float4*)Xs)[q] = ((const float4*)Xp)[((size_t)(b*128 + scn*32+sl))*256 + jt*64 + p4];
    }
    __syncthreads();
    for(int sl=0; sl<32; sl++){
      float4 xv = ((const float4*)Xs)[sl*64+tj];
      #pragma unroll
      for(int k=0;k<4;k++){
        float pa = Pt[sl*17 + tc*4+k];
        acc[k].x += pa*xv.x; acc[k].y += pa*xv.y;
        acc[k].z += pa*xv.z; acc[k].w += pa*xv.w;
      }
    }
  }
  #pragma unroll
  for(int k=0;k<4;k++){
    ((float4*)Zc)[((size_t)((b*8+o)*128 + c0+tc*4+k))*256 + jt*64 + tj] = acc[k];
  }
}

// corner corrections -> Bc (512 modes per map)
__global__ __launch_bounds__(256) void k_corr(
  const float* __restrict__ Zc,
  const float* __restrict__ kqv_wr, const float* __restrict__ kqv_wi,
  const float* __restrict__ kqv_bias, const float* __restrict__ kqv_sw, const float* __restrict__ kqv_sb,
  const float* __restrict__ p_wr, const float* __restrict__ p_wi,
  const float* __restrict__ p_bias, const float* __restrict__ p_sw, const float* __restrict__ p_sb,
  float2* __restrict__ Bc)
{
  const float2* Z2 = (const float2*)Zc;
  const int m = blockIdx.x;
  const int b = m>>7, cix = m&127;
  const int tid = threadIdx.x;
  for(int j=tid; j<512; j+=256){
    int r = j>>4, c = j&15;
    int ky = (r<16)? r : 96+r;
    float accr=0.f, acci=0.f;
    int rp = -1;
    if(c==0){ int kyp = (128-ky)&127; rp = (kyp<16)? kyp : ((kyp>=112)? kyp-96 : -1); }
    for(int o=0;o<8;o++){
      size_t zoff = ((size_t)((b*8+o)*128 + cix))*512;
      float2 z = Z2[zoff+j];
      float cvr=0.f, cvi=0.f;
      bool inV = (c<8) && (ky<8 || ky>=120);
      if(inV){
        int vrow = (ky<8)? ky : 8+(ky-120);
        float wr = kqv_wr[((16+o)*16+vrow)*8+c], wi = kqv_wi[((16+o)*16+vrow)*8+c];
        cvr = wr*z.x - wi*z.y; cvi = wr*z.y + wi*z.x;
      }
      float ar = cvr, ai = cvi;
      if(c==0){
        float pvr=0.f, pvi=0.f;
        int kyp = (128-ky)&127;
        bool pInV = (kyp<8 || kyp>=120);
        if(pInV && rp>=0){
          int vrow = (kyp<8)? kyp : 8+(kyp-120);
          float2 z2 = Z2[zoff + rp*16];
          float wr = kqv_wr[((16+o)*16+vrow)*8], wi = kqv_wi[((16+o)*16+vrow)*8];
          pvr = wr*z2.x - wi*z2.y; pvi = wr*z2.y + wi*z2.x;
        }
        ar = 0.5f*(cvr + pvr);
        ai = 0.5f*(cvi - pvi);
      }
      float sv = kqv_sw[16+o];
      float Dv = kqv_bias[16+o] + kqv_sb[16+o];
      float atr = sv*z.x + ar + ((j==0)? Dv : 0.f);
      float ati = sv*z.y + ai;
      float psw = p_sw[o];
      accr += psw*ar;  acci += psw*ai;
      float wpr = p_wr[(o*32+r)*16+c], wpi = p_wi[(o*32+r)*16+c];
      accr += wpr*atr - wpi*ati;
      acci += wpr*ati + wpi*atr;
      if(j==0) accr += psw*Dv;
    }
    if(j==0) accr += p_bias[0] + p_sb[0];
    Bc[m*512+j] = make_float2(accr, acci);
  }
}

// ---------------- attn GEMM: y0g[b,c][p] = sum_s PA^T[s][c] * x[s][p] + pbeta --
__global__ __launch_bounds__(256) void k_attn_gemm(
  const float* __restrict__ PAT, const float* __restrict__ xin,
  const float* __restrict__ pbeta, float* __restrict__ y0g)
{
  __shared__ float PAs[32*33];
  __shared__ float Xs[32*256];
  const int bid = blockIdx.x;
  const int b = bid>>8, ct = (bid>>6)&3, pt = bid&63;
  const int t = threadIdx.x;
  const int tc = t>>6, tp = t&63;
  float4 acc[8];
  #pragma unroll
  for(int k=0;k<8;k++) acc[k] = make_float4(0.f,0.f,0.f,0.f);
  for(int sc4=0; sc4<4; sc4++){
    __syncthreads();
    for(int idx=t; idx<1024; idx+=256){
      int sl = idx>>5, cl = idx&31;
      PAs[sl*33+cl] = PAT[((size_t)(b*128 + sc4*32+sl))*128 + ct*32+cl];
    }
    for(int q=t; q<2048; q+=256){
      int sl = q>>6, p4 = q&63;
      ((float4*)Xs)[q] =
        ((const float4*)xin)[((size_t)(b*128 + sc4*32+sl))*4096 + pt*64 + p4];
    }
    __syncthreads();
    for(int sl=0; sl<32; sl++){
      float4 xv = ((const float4*)Xs)[sl*64+tp];
      #pragma unroll
      for(int k=0;k<8;k++){
        float pa = PAs[sl*33 + tc*8+k];
        acc[k].x += pa*xv.x; acc[k].y += pa*xv.y;
        acc[k].z += pa*xv.z; acc[k].w += pa*xv.w;
      }
    }
  }
  #pragma unroll
  for(int k=0;k<8;k++){
    int c = ct*32 + tc*8 + k;
    float pb = pbeta[b*128+c];
    float4 o = acc[k];
    o.x += pb; o.y += pb; o.z += pb; o.w += pb;
    ((float4*)y0g)[((size_t)(b*128+c))*4096 + pt*64 + tp] = o;
  }
}

// ---------------- epi0: attn = IN(y0g + cinv(Bc) + x)*aw+ab ; emit alpha2/beta2
__global__ __launch_bounds__(256) void k_epi0(
  const float* __restrict__ y0g, const float* __restrict__ xin,
  const float2* __restrict__ Bc,
  const float2* __restrict__ CS,
  const float* __restrict__ awp, const float* __restrict__ abp,
  const float* __restrict__ n2w, const float* __restrict__ n2b,
  float* __restrict__ attn, float* __restrict__ a2, float* __restrict__ b2)
{
  __shared__ float2 Bcl[512];
  __shared__ float2 V[128*17];
  __shared__ float red[512];
  const int m = blockIdx.x, t = threadIdx.x;
  for(int j=t;j<512;j+=256) Bcl[j] = Bc[m*512+j];
  __syncthreads();
  #pragma unroll
  for(int k=0;k<8;k++){
    int idx = t + 256*k;
    int mm = idx>>4, c = idx&15;
    float vr=0.f, vi=0.f;
    for(int r=0;r<32;r++){
      int ky = (r<16)? r : 96+r;
      float2 bc = Bcl[r*16+c];
      float2 cs = CS[128 + ((ky*mm)&127)];
      vr += bc.x*cs.x - bc.y*cs.y;
      vi += bc.x*cs.y + bc.y*cs.x;
    }
    float w = (c==0)?1.0f:2.0f;
    V[mm*17+c] = make_float2(vr*w, vi*w);
  }
  __syncthreads();
  const float4* x4 = (const float4*)(xin + (size_t)m*16384);
  const float4* g4 = (const float4*)(y0g + (size_t)m*16384);
  float s1=0.f, s2=0.f;
  for(int k=0;k<16;k++){
    int q = t + 256*k;
    int mm = q>>5, n0 = (q&31)*4;
    float4 xv = x4[q], gv = g4[q];
    float vv[4] = {xv.x+gv.x, xv.y+gv.y, xv.z+gv.z, xv.w+gv.w};
    #pragma unroll
    for(int d=0;d<4;d++){
      int n = n0+d;
      float cv = 0.f;
      #pragma unroll
      for(int c=0;c<16;c++){
        float2 v2 = V[mm*17+c];
        float2 cs = CS[c*128+n];
        cv += v2.x*cs.x - v2.y*cs.y;
      }
      float v = vv[d] + cv;
      s1 += v; s2 += v*v;
    }
  }
  blockReduce2(s1,s2,red);
  float mu = s1*(1.0f/16384.0f);
  float var = s2*(1.0f/16384.0f)-mu*mu;
  float rs = rsqrtf(var+1e-5f);
  float aw = awp[0], ab = abp[0];
  float4* at4 = (float4*)(attn + (size_t)m*16384);
  for(int k=0;k<16;k++){
    int q = t + 256*k;
    int mm = q>>5, n0 = (q&31)*4;
    float4 xv = x4[q], gv = g4[q];
    float vv[4] = {xv.x+gv.x, xv.y+gv.y, xv.z+gv.z, xv.w+gv.w};
    float4 ov;
    float* op = &ov.x;
    #pragma unroll
    for(int d=0;d<4;d++){
      int n = n0+d;
      float cv = 0.f;
      #pragma unroll
      for(int c=0;c<16;c++){
        float2 v2 = V[mm*17+c];
        float2 cs = CS[c*128+n];
        cv += v2.x*cs.x - v2.y*cs.y;
      }
      op[d] = (vv[d] + cv - mu)*rs*aw + ab;
    }
    at4[q] = ov;
  }
  if(t==0){
    float va = aw*aw*var/(var+1e-5f);
    float al = n2w[m&3]*rsqrtf(va+1e-5f);
    a2[m] = al; b2[m] = n2b[m&3] - ab*al;
  }
}

// ---------------- corner rfft2 (32 rows x 16 cols) of a spatial map ------------
__global__ __launch_bounds__(256) void k_rfft_corner(
  const float* __restrict__ z, const float* __restrict__ alpha,
  const float* __restrict__ dcv, const int dcmask,
  const float2* __restrict__ CS, float2* __restrict__ Hc)
{
  __shared__ float zl[32*129];
  __shared__ float2 Rc[128*17];
  const int m = blockIdx.x, t = threadIdx.x;
  const int yl = t&31, cg = t>>5;
  for(int yc=0; yc<4; yc++){
    __syncthreads();
    {
      const float4* zp4 = (const float4*)(z + (size_t)m*16384 + yc*4096);
      for(int i4=t;i4<1024;i4+=256){
        float4 v = zp4[i4];
        int y = i4>>5, n = (i4&31)*4;
        zl[y*129+n]=v.x; zl[y*129+n+1]=v.y; zl[y*129+n+2]=v.z; zl[y*129+n+3]=v.w;
      }
    }
    __syncthreads();
    #pragma unroll
    for(int k=0;k<2;k++){
      int c = cg + 8*k;
      float ar=0.f, ai=0.f;
      for(int n=0;n<128;n++){
        float zv = zl[yl*129+n];
        float2 cs = CS[c*128+n];
        ar += zv*cs.x; ai -= zv*cs.y;
      }
      Rc[(yc*32+yl)*17 + c] = make_float2(ar, ai);
    }
  }
  __syncthreads();
  const float sc = (alpha ? alpha[m] : 1.0f) * (1.0f/16384.0f);
  #pragma unroll
  for(int k=0;k<2;k++){
    int idx = t + 256*k;
    int r = idx>>4, c = idx&15;
    int ky = (r<16)? r : 96+r;
    float hr=0.f, hi=0.f;
    for(int y=0;y<128;y++){
      float2 Rv = Rc[y*17+c];
      float2 cs = CS[128 + ((ky*y)&127)];
      hr += Rv.x*cs.x + Rv.y*cs.y;
      hi += Rv.y*cs.x - Rv.x*cs.y;
    }
    float2 o = make_float2(hr*sc, hi*sc);
    if(idx==0 && dcv) o = make_float2(dcv[m&dcmask], 0.f);
    Hc[m*512+idx] = o;
  }
}

// ---------------- mixer spectral: S = sum_i w.Hc ; IN in freq -> Sn ------------
__global__ __launch_bounds__(256) void k_mixc(
  const float2* __restrict__ Hc,
  const float* __restrict__ wr0, const float* __restrict__ wi0,
  float2* __restrict__ Sn)
{
  __shared__ float2 Sl[512];
  __shared__ float red[512];
  const int m = blockIdx.x;
  const int g = m>>2, o = m&3;
  const int t = threadIdx.x;
  for(int j=t;j<512;j+=256){
    int r = j>>4, c = j&15;
    float ar=0.f, ai=0.f;
    for(int i2=0;i2<4;i2++){
      float2 h = Hc[(g*4+i2)*512 + j];
      float wr = wr0[((i2*4+o)*32+r)*16+c], wi = wi0[((i2*4+o)*32+r)*16+c];
      ar += wr*h.x - wi*h.y; ai += wr*h.y + wi*h.x;
    }
    Sl[j] = make_float2(ar, ai);
  }
  __syncthreads();
  float vs=0.f, dummy=0.f;
  for(int j=t;j<512;j+=256){
    int c=j&15;
    if(c>=1) vs += 2.0f*(Sl[j].x*Sl[j].x + Sl[j].y*Sl[j].y);
  }
  if(t<32){
    int ky = (t<16)? (t+1) : (96+t);
    float ar=0.f, ai=0.f;
    if(ky<16){ ar=Sl[ky*16].x; ai=Sl[ky*16].y; }
    else if(ky>=112){ int r=ky-96; ar=Sl[r*16].x; ai=Sl[r*16].y; }
    int kyp = 128-ky;
    float br2=0.f, bi2=0.f;
    if(kyp<16){ br2=Sl[kyp*16].x; bi2=Sl[kyp*16].y; }
    else if(kyp>=112){ int r=kyp-96; br2=Sl[r*16].x; bi2=Sl[r*16].y; }
    float pr = 0.5f*(ar+br2), pi = 0.5f*(ai-bi2);
    vs += pr*pr + pi*pi;
  }
  blockReduce2(vs, dummy, red);
  float rs2 = rsqrtf(vs + 1e-5f);
  for(int j=t;j<512;j+=256){
    float2 s = Sl[j];
    if(j==0) Sn[m*512+j] = make_float2(0.f,0.f);
    else     Sn[m*512+j] = make_float2(s.x*rs2, s.y*rs2);
  }
}

// ---------------- mixer inverse: out = [gelu]( sum_i cw*in_i + cb + cinv(Sn) ) -
__global__ __launch_bounds__(256) void k_mixinv(
  const float2* __restrict__ Sn, const float* __restrict__ inmaps,
  const float* __restrict__ a2, const float* __restrict__ b2,
  const float* __restrict__ msw, const float* __restrict__ msb,
  const float2* __restrict__ CS, const int dogelu, float* __restrict__ outp)
{
  __shared__ float2 Sl[512];
  __shared__ float2 V[128*17];
  const int m = blockIdx.x;
  const int g = m>>2, o = m&3;
  const int t = threadIdx.x;
  float cw[4]; float cb = msb[o];
  #pragma unroll
  for(int i=0;i<4;i++){
    float al = a2 ? a2[g*4+i] : 1.0f;
    float be = b2 ? b2[g*4+i] : 0.0f;
    float sw = msw[o*4+i];
    cw[i] = sw*al; cb += sw*be;
  }
  for(int j=t;j<512;j+=256) Sl[j] = Sn[m*512+j];
  __syncthreads();
  #pragma unroll
  for(int k=0;k<8;k++){
    int idx = t + 256*k;
    int mm = idx>>4, c = idx&15;
    float vr=0.f, vi=0.f;
    for(int r=0;r<32;r++){
      int ky = (r<16)? r : 96+r;
      float2 bc = Sl[r*16+c];
      float2 cs = CS[128 + ((ky*mm)&127)];
      vr += bc.x*cs.x - bc.y*cs.y;
      vi += bc.x*cs.y + bc.y*cs.x;
    }
    float w = (c==0)?1.0f:2.0f;
    V[mm*17+c] = make_float2(vr*w, vi*w);
  }
  __syncthreads();
  const float4* in4 = (const float4*)(inmaps + (size_t)(g*4)*16384);
  float4* o4 = (float4*)(outp + (size_t)m*16384);
  for(int k=0;k<16;k++){
    int q = t + 256*k;
    int mm = q>>5, n0 = (q&31)*4;
    float4 v0 = in4[q], v1 = in4[4096+q], v2 = in4[8192+q], v3 = in4[12288+q];
    float4 ov;
    float* op = &ov.x;
    float base[4] = {
      cb + cw[0]*v0.x + cw[1]*v1.x + cw[2]*v2.x + cw[3]*v3.x,
      cb + cw[0]*v0.y + cw[1]*v1.y + cw[2]*v2.y + cw[3]*v3.y,
      cb + cw[0]*v0.z + cw[1]*v1.z + cw[2]*v2.z + cw[3]*v3.z,
      cb + cw[0]*v0.w + cw[1]*v1.w + cw[2]*v2.w + cw[3]*v3.w };
    #pragma unroll
    for(int d=0;d<4;d++){
      int n = n0+d;
      float cv = 0.f;
      #pragma unroll
      for(int c=0;c<16;c++){
        float2 vv = V[mm*17+c];
        float2 cs = CS[c*128+n];
        cv += vv.x*cs.x - vv.y*cs.y;
      }
      float val = base[d] + cv;
      if(dogelu) val = 0.5f*val*(1.0f+erff(val*0.70710678118f));
      op[d] = val;
    }
    o4[q] = ov;
  }
}

// ---------------- final: out = IN(h2)*mw+mb + attn -----------------------------
__global__ __launch_bounds__(256) void k_epi2(
    const float* __restrict__ h2, const float* __restrict__ attn,
    const float* __restrict__ mw, const float* __restrict__ mbv,
    float* __restrict__ outp)
{
  __shared__ float red[512];
  const int m = blockIdx.x, t = threadIdx.x;
  const float4* h4 = (const float4*)(h2 + (size_t)m*16384);
  const float4* a4 = (const float4*)(attn + (size_t)m*16384);
  float4* o4 = (float4*)(outp + (size_t)m*16384);
  float s1=0.f, s2=0.f;
  for(int i=t;i<4096;i+=256){
    float4 v = h4[i];
    s1 += v.x+v.y+v.z+v.w;
    s2 += v.x*v.x+v.y*v.y+v.z*v.z+v.w*v.w;
  }
  blockReduce2(s1,s2,red);
  float mu = s1*(1.0f/16384.0f);
  float var = s2*(1.0f/16384.0f)-mu*mu;
  float rs = rsqrtf(var+1e-5f);
  float w = mw[m&3], b = mbv[m&3];
  for(int i=t;i<4096;i+=256){
    float4 v = h4[i], av = a4[i];
    float4 ov;
    ov.x = (v.x-mu)*rs*w + b + av.x;
    ov.y = (v.y-mu)*rs*w + b + av.y;
    ov.z = (v.z-mu)*rs*w + b + av.z;
    ov.w = (v.w-mu)*rs*w + b + av.w;
    o4[i] = ov;
  }
}

extern "C" void kernel_launch(void* const* d_in, const int* in_sizes, int n_in,
                              void* d_out, int out_size, void* d_ws, size_t ws_size,
                              hipStream_t stream)
{
  const float* x        = (const float*)d_in[0];
  const float* norm1_w  = (const float*)d_in[1];
  const float* norm1_b  = (const float*)d_in[2];
  const float* kqv_wr   = (const float*)d_in[3];
  const float* kqv_wi   = (const float*)d_in[4];
  const float* kqv_bias = (const float*)d_in[5];
  const float* kqv_sw   = (const float*)d_in[6];
  const float* kqv_sb   = (const float*)d_in[7];
  const float* p_wr     = (const float*)d_in[8];
  const float* p_wi     = (const float*)d_in[9];
  const float* p_bias   = (const float*)d_in[10];
  const float* p_sw     = (const float*)d_in[11];
  const float* p_sb     = (const float*)d_in[12];
  const float* attn_norm_w = (const float*)d_in[13];
  const float* attn_norm_b = (const float*)d_in[14];
  const float* norm2_w  = (const float*)d_in[15];
  const float* norm2_b  = (const float*)d_in[16];
  const float* mix_wr   = (const float*)d_in[17];
  const float* mix_wi   = (const float*)d_in[18];
  // mix_bias (d_in[19]) only shifts the spectral mean which IN removes -> unused
  const float* mix_sw   = (const float*)d_in[20];
  const float* mix_sb   = (const float*)d_in[21];
  const float* mon_w    = (const float*)d_in[22];
  const float* mon_b    = (const float*)d_in[23];
  float* out = (float*)d_out;

  const size_t NEED = (size_t)26576128 * sizeof(float);
  if(ws_size < NEED) return;

  float* ws = (float*)d_ws;
  size_t off = 0;
  float2* CS  = (float2*)(ws + off); off += 32768;
  float* a1   = ws + off; off += 256;
  float* b1   = ws + off; off += 256;
  float* a2   = ws + off; off += 256;
  float* b2   = ws + off; off += 256;
  float* pbeta= ws + off; off += 256;
  float* Xtr  = ws + off; off += 540672;
  float* Xti  = ws + off; off += 540672;
  float* pool = ws + off; off += 17301504;
  float* P    = ws + off; off += 262144;
  float* PAT  = ws + off; off += 32768;
  float2* Xp  = (float2*)(ws + off); off += 262144;
  float* Zc   = ws + off; off += 2097152;
  float2* Bc  = (float2*)(ws + off); off += 262144;
  float* attn = ws + off; off += 4194304;
  float2* Hc  = (float2*)(ws + off); off += 524288;
  float2* Sn  = (float2*)(ws + off); off += 524288;

  float* Pp   = attn;                  // 16 x 262144 partials, dead before epi0

  // pool slots (4 x 4325376)
  float* R1r = pool;                   // dead after k_p2
  float* R1i = pool + 1081344;
  float2* Qc = (float2*)pool;                      // 8650752 floats
  float2* Kc = (float2*)(pool + 8650752);          // 8650752 floats
  float* y0g = pool;                   // after scores (Q dead)
  float* h1  = pool + 4325376;
  float* h2  = pool + 8650752;

  k_tables<<<dim3(128), dim3(128), 0, stream>>>(CS);
  k_instats<<<dim3(256), dim3(256), 0, stream>>>(x, norm1_w, norm1_b, a1, b1);
  k_p1<<<dim3(1024), dim3(256), 0, stream>>>(x, R1r, R1i, CS);
  k_p2<<<dim3(256), dim3(704), 0, stream>>>(R1r, R1i, CS, a1, norm1_b, Xtr, Xti);
  k_build_qk<<<dim3(2048), dim3(256), 0, stream>>>(Xtr, Xti, kqv_wr, kqv_wi, kqv_bias,
                                                   kqv_sw, kqv_sb, Qc, Kc);
  k_scores<<<dim3(1024), dim3(256), 0, stream>>>(Qc, Kc, Pp);
  k_softmax<<<dim3(2048), dim3(64), 0, stream>>>(Pp, P);
  k_peff<<<dim3(128), dim3(256), 0, stream>>>(P, p_sw, kqv_sw, a1, PAT);
  k_pbeta<<<dim3(256), dim3(128), 0, stream>>>(P, p_sw, kqv_sw, b1, pbeta);
  k_gather<<<dim3(256), dim3(256), 0, stream>>>(Xtr, Xti, Xp);
  k_zp<<<dim3(512), dim3(256), 0, stream>>>(P, (const float*)Xp, Zc);
  k_corr<<<dim3(256), dim3(256), 0, stream>>>(Zc, kqv_wr, kqv_wi, kqv_bias, kqv_sw, kqv_sb,
                                              p_wr, p_wi, p_bias, p_sw, p_sb, Bc);
  k_attn_gemm<<<dim3(512), dim3(256), 0, stream>>>(PAT, x, pbeta, y0g);
  k_epi0<<<dim3(256), dim3(256), 0, stream>>>(y0g, x, Bc, CS, attn_norm_w, attn_norm_b,
                                              norm2_w, norm2_b, attn, a2, b2);
  // mixer layer 1
  k_rfft_corner<<<dim3(256), dim3(256), 0, stream>>>(attn, a2, norm2_b, 3, CS, Hc);
  k_mixc<<<dim3(256), dim3(256), 0, stream>>>(Hc, mix_wr, mix_wi, Sn);
  k_mixinv<<<dim3(256), dim3(256), 0, stream>>>(Sn, attn, a2, b2, mix_sw, mix_sb, CS, 1, h1);
  // mixer layer 2
  k_rfft_corner<<<dim3(256), dim3(256), 0, stream>>>(h1, (const float*)nullptr,
                                                     (const float*)nullptr, 0, CS, Hc);
  k_mixc<<<dim3(256), dim3(256), 0, stream>>>(Hc, mix_wr+8192, mix_wi+8192, Sn);
  k_mixinv<<<dim3(256), dim3(256), 0, stream>>>(Sn, h1, (const float*)nullptr, (const float*)nullptr,
                                                mix_sw+16, mix_sb+4, CS, 0, h2);
  k_epi2<<<dim3(256), dim3(256), 0, stream>>>(h2, attn, mon_w, mon_b, out);
}